// Round 5
// baseline (781.899 us; speedup 1.0000x reference)
//
#include <hip/hip_runtime.h>
#include <math.h>

#define BATCH 4096
#define T 128
#define HOR 24
#define HPS 17                     // sh_hp stride (odd -> conflict-free columns)

#define LOG2E 1.44269504088896f
#define C2    2.88539008177793f   // 2*log2(e)

typedef _Float16 half2_t __attribute__((ext_vector_type(2)));
typedef float f2  __attribute__((ext_vector_type(2)));
typedef float f4v __attribute__((ext_vector_type(4)));

__device__ __forceinline__ float fexp2(float x){ return __builtin_amdgcn_exp2f(x); }
__device__ __forceinline__ float frcp(float x){ return __builtin_amdgcn_rcpf(x); }
__device__ __forceinline__ float fsig(float x){ return frcp(1.0f + fexp2(-LOG2E*x)); }
__device__ __forceinline__ float ftanh(float x){ return fmaf(-2.0f, frcp(1.0f + fexp2(C2*x)), 1.0f); }
__device__ __forceinline__ half2_t bch(unsigned u){ return __builtin_bit_cast(half2_t,u); }
__device__ __forceinline__ unsigned pk2(float a,float b){ return __builtin_bit_cast(unsigned, __builtin_amdgcn_cvt_pkrtz(a,b)); }
__device__ __forceinline__ float fdot2f(half2_t a, half2_t b, float c){
#if __has_builtin(__builtin_amdgcn_fdot2)
  return __builtin_amdgcn_fdot2(a,b,c,false);
#else
  return fmaf((float)a.x,(float)b.x, fmaf((float)a.y,(float)b.y,c));
#endif
}
__device__ __forceinline__ f2 pkfma(f2 a, f2 b, f2 c){ return __builtin_elementwise_fma(a,b,c); }

// One wave per batch element (blockDim=64). Wave-synchronous: DS ops from a
// single wave execute in order -> ZERO barriers in the whole kernel.
// Lane l owns h[l]/d[l]; GRU rows l,64+l,128+l packed fp16 in VGPRs.
__global__ __launch_bounds__(64, 3)
void darnn_kernel(const float* __restrict__ x,
                  const float* __restrict__ W_ih_e, const float* __restrict__ W_hh_e,
                  const float* __restrict__ b_ih_e, const float* __restrict__ b_hh_e,
                  const float* __restrict__ W_init, const float* __restrict__ b_init,
                  const float* __restrict__ W_ih_d, const float* __restrict__ W_hh_d,
                  const float* __restrict__ b_ih_d, const float* __restrict__ b_hh_d,
                  const float* __restrict__ W_d, const float* __restrict__ U_d,
                  const float* __restrict__ v_d, const float* __restrict__ W_out,
                  const float* __restrict__ b_out, const float* __restrict__ y0,
                  float* __restrict__ out)
{
  const int l = threadIdx.x;            // 0..63
  const int b = blockIdx.x;
  const int a    = l & 31;
  const int half = l >> 5;

  __shared__ __align__(16) unsigned  sh_hp[T*HPS];  // 8704 B: cols 0..15 = Hp fp16x2 (pre-scaled C2), col 16 = hw[t] bits
  __shared__ __align__(16) float     sh_x[T];       // 512 B  (reused: [0..63] = h_T fp32 after encoder)
  __shared__ __align__(16) float     sh_dp[32];     // 128 B  d_proj (pre-scaled C2)
  __shared__ __align__(16) _Float16  sh_h16[64];    // 128 B  h (later d) fp16

  unsigned wr_r[32], wr_z[32], wr_n[32];  // GRU W_hh rows, fp16-packed (96 VGPR)
  unsigned udr[16];                        // U_d (later W_d) row a / half (16 VGPR)

  // ---------------- stage ----------------
  {
    const f4v* wp = (const f4v*)W_hh_e;
    #pragma unroll
    for (int k = 0; k < 16; ++k) {
      f4v vr = wp[l*16 + k];
      f4v vz = wp[(64 + l)*16 + k];
      f4v vn = wp[(128 + l)*16 + k];
      wr_r[2*k] = pk2(vr.x, vr.y); wr_r[2*k+1] = pk2(vr.z, vr.w);
      wr_z[2*k] = pk2(vz.x, vz.y); wr_z[2*k+1] = pk2(vz.z, vz.w);
      wr_n[2*k] = pk2(vn.x, vn.y); wr_n[2*k+1] = pk2(vn.z, vn.w);
    }
  }
  float wih0 = W_ih_e[l], wih1 = W_ih_e[64+l], wih2 = W_ih_e[128+l];
  float bb0  = b_ih_e[l] + b_hh_e[l];
  float bb1  = b_ih_e[64+l] + b_hh_e[64+l];
  float bih2 = b_ih_e[128+l], bhh2 = b_hh_e[128+l];
  float wo2l = W_out[64 + l];
  {
    f2 g = ((const f2*)(x + (size_t)b * T))[l];
    sh_x[2*l] = g.x; sh_x[2*l+1] = g.y;
  }
  sh_h16[l] = (_Float16)0.0f;
  {  // U_d row a, half `half` -> registers (lane only ever needs its own column)
    const f2* up = (const f2*)(U_d + a*64 + half*32);
    #pragma unroll
    for (int k = 0; k < 16; ++k) { f2 f = up[k]; udr[k] = pk2(f.x, f.y); }
  }

  // ---------------- encoder: 128 steps, wave-synchronous ----------------
  // input-attention is identity (softmax over size-1 axis == 1).
  float hprev = 0.0f;
  #pragma unroll 2
  for (int t = 0; t < T; ++t) {
    // all three gates share one pass over h16 (8 uint4 broadcast reads)
    float ar0=0.f, ar1=0.f, az0=0.f, az1=0.f, an0=0.f, an1=0.f;
    {
      const uint4* hq = (const uint4*)sh_h16;
      #pragma unroll
      for (int q = 0; q < 8; ++q) {
        uint4 hv = hq[q];
        ar0 = fdot2f(bch(hv.x), bch(wr_r[4*q+0]), ar0);
        az0 = fdot2f(bch(hv.x), bch(wr_z[4*q+0]), az0);
        an0 = fdot2f(bch(hv.x), bch(wr_n[4*q+0]), an0);
        ar1 = fdot2f(bch(hv.y), bch(wr_r[4*q+1]), ar1);
        az1 = fdot2f(bch(hv.y), bch(wr_z[4*q+1]), az1);
        an1 = fdot2f(bch(hv.y), bch(wr_n[4*q+1]), an1);
        ar0 = fdot2f(bch(hv.z), bch(wr_r[4*q+2]), ar0);
        az0 = fdot2f(bch(hv.z), bch(wr_z[4*q+2]), az0);
        an0 = fdot2f(bch(hv.z), bch(wr_n[4*q+2]), an0);
        ar1 = fdot2f(bch(hv.w), bch(wr_r[4*q+3]), ar1);
        az1 = fdot2f(bch(hv.w), bch(wr_z[4*q+3]), az1);
        an1 = fdot2f(bch(hv.w), bch(wr_n[4*q+3]), an1);
      }
    }
    float xt = sh_x[t];
    float r = fsig(fmaf(xt, wih0, bb0) + ar0 + ar1);
    float z = fsig(fmaf(xt, wih1, bb1) + az0 + az1);
    float n = ftanh(fmaf(xt, wih2, bih2) + r * (an0 + an1 + bhh2));
    float hnew = fmaf(z, hprev - n, n);
    hprev = hnew;
    sh_h16[l] = (_Float16)hnew;          // DS in-order: later reads see this
    // Hp[t][a] (pre-scaled by C2, fp16-packed)
    {
      float acc = 0.f;
      const uint4* hb16 = (const uint4*)(sh_h16 + 32*half);
      #pragma unroll
      for (int kk = 0; kk < 4; ++kk) {
        uint4 hv = hb16[kk];
        acc = fdot2f(bch(hv.x), bch(udr[4*kk+0]), acc);
        acc = fdot2f(bch(hv.y), bch(udr[4*kk+1]), acc);
        acc = fdot2f(bch(hv.z), bch(udr[4*kk+2]), acc);
        acc = fdot2f(bch(hv.w), bch(udr[4*kk+3]), acc);
      }
      acc += __shfl_xor(acc, 32);        // combine halves -> lanes 0..31 hold a
      acc *= C2;
      float accn = __shfl_down(acc, 1);
      if (l < 32 && !(l & 1))
        sh_hp[t*HPS + (l >> 1)] = pk2(acc, accn);
    }
    // hw[t] = W_out2 . h_t  -> sh_hp col 16
    {
      float p = wo2l * hnew;
      #pragma unroll
      for (int o = 32; o > 0; o >>= 1) p += __shfl_xor(p, o);
      if (l == 0) sh_hp[t*HPS + 16] = __builtin_bit_cast(unsigned, p);
    }
  }

  // ---------------- decoder prep ----------------
  sh_x[l] = hprev;                       // h_T fp32 (sh_x free after encoder)
  float dprev;
  {  // d0 = h_T @ W_init.T + b_init  (fp32 packed fma)
    const f4v* wi = (const f4v*)(W_init + l*64);
    const f4v* hb = (const f4v*)sh_x;
    f2 a0 = {0.f,0.f}, a1 = {0.f,0.f};
    #pragma unroll
    for (int k = 0; k < 16; ++k) {
      f4v wv = wi[k]; f4v hv = hb[k];
      a0 = pkfma(wv.xy, hv.xy, a0);
      a1 = pkfma(wv.zw, hv.zw, a1);
    }
    dprev = b_init[l] + (a0.x + a0.y) + (a1.x + a1.y);
  }
  {  // reload GRU weights with decoder W_hh
    const f4v* wp = (const f4v*)W_hh_d;
    #pragma unroll
    for (int k = 0; k < 16; ++k) {
      f4v vr = wp[l*16 + k];
      f4v vz = wp[(64 + l)*16 + k];
      f4v vn = wp[(128 + l)*16 + k];
      wr_r[2*k] = pk2(vr.x, vr.y); wr_r[2*k+1] = pk2(vr.z, vr.w);
      wr_z[2*k] = pk2(vz.x, vz.y); wr_z[2*k+1] = pk2(vz.z, vz.w);
      wr_n[2*k] = pk2(vn.x, vn.y); wr_n[2*k+1] = pk2(vn.z, vn.w);
    }
  }
  wih0 = W_ih_d[l]; wih1 = W_ih_d[64+l]; wih2 = W_ih_d[128+l];
  bb0  = b_ih_d[l] + b_hh_d[l];
  bb1  = b_ih_d[64+l] + b_hh_d[64+l];
  bih2 = b_ih_d[128+l]; bhh2 = b_hh_d[128+l];
  {  // W_d row -> udr (overwrites U_d row)
    const f2* up = (const f2*)(W_d + a*64 + half*32);
    #pragma unroll
    for (int k = 0; k < 16; ++k) { f2 f = up[k]; udr[k] = pk2(f.x, f.y); }
  }
  float wout1 = W_out[l];
  float hw0 = __builtin_bit_cast(float, sh_hp[l*HPS + 16]);
  float hw1 = __builtin_bit_cast(float, sh_hp[(64 + l)*HPS + 16]);
  float oprev = y0[0];
  float bo = b_out[0];
  float c1;                              // log2e * sum(v_d)
  {
    float sv = v_d[a];
    sv += __shfl_xor(sv, 16); sv += __shfl_xor(sv, 8);
    sv += __shfl_xor(sv, 4);  sv += __shfl_xor(sv, 2); sv += __shfl_xor(sv, 1);
    c1 = LOG2E * sv;
  }
  sh_h16[l] = (_Float16)dprev;

  const unsigned* hpr0 = sh_hp + l*HPS;
  const unsigned* hpr1 = sh_hp + (64 + l)*HPS;

  // ---------------- decoder: 24 steps, wave-synchronous ----------------
  for (int s = 0; s < HOR; ++s) {
    // GRU matvec (shared h16 pass) + combine
    float ar0=0.f, ar1=0.f, az0=0.f, az1=0.f, an0=0.f, an1=0.f;
    {
      const uint4* hq = (const uint4*)sh_h16;
      #pragma unroll
      for (int q = 0; q < 8; ++q) {
        uint4 hv = hq[q];
        ar0 = fdot2f(bch(hv.x), bch(wr_r[4*q+0]), ar0);
        az0 = fdot2f(bch(hv.x), bch(wr_z[4*q+0]), az0);
        an0 = fdot2f(bch(hv.x), bch(wr_n[4*q+0]), an0);
        ar1 = fdot2f(bch(hv.y), bch(wr_r[4*q+1]), ar1);
        az1 = fdot2f(bch(hv.y), bch(wr_z[4*q+1]), az1);
        an1 = fdot2f(bch(hv.y), bch(wr_n[4*q+1]), an1);
        ar0 = fdot2f(bch(hv.z), bch(wr_r[4*q+2]), ar0);
        az0 = fdot2f(bch(hv.z), bch(wr_z[4*q+2]), az0);
        an0 = fdot2f(bch(hv.z), bch(wr_n[4*q+2]), an0);
        ar1 = fdot2f(bch(hv.w), bch(wr_r[4*q+3]), ar1);
        az1 = fdot2f(bch(hv.w), bch(wr_z[4*q+3]), az1);
        an1 = fdot2f(bch(hv.w), bch(wr_n[4*q+3]), an1);
      }
    }
    float r = fsig(fmaf(oprev, wih0, bb0) + ar0 + ar1);
    float z = fsig(fmaf(oprev, wih1, bb1) + az0 + az1);
    float n = ftanh(fmaf(oprev, wih2, bih2) + r * (an0 + an1 + bhh2));
    float dnew = fmaf(z, dprev - n, n);
    dprev = dnew;
    sh_h16[l] = (_Float16)dnew;
    // d_proj[a] (pre-scaled C2) -> sh_dp
    {
      float acc = 0.f;
      const uint4* db16 = (const uint4*)(sh_h16 + 32*half);
      #pragma unroll
      for (int kk = 0; kk < 4; ++kk) {
        uint4 dv = db16[kk];
        acc = fdot2f(bch(dv.x), bch(udr[4*kk+0]), acc);
        acc = fdot2f(bch(dv.y), bch(udr[4*kk+1]), acc);
        acc = fdot2f(bch(dv.z), bch(udr[4*kk+2]), acc);
        acc = fdot2f(bch(dv.w), bch(udr[4*kk+3]), acc);
      }
      acc += __shfl_xor(acc, 32);
      if (l < 32) sh_dp[l] = C2 * acc;
    }
    // scores rows t0=l, t1=64+l: score = SV - 2*sum_a v_a*sig2(dps+hps)
    float rs0 = 0.f, rs1 = 0.f;
    #pragma unroll
    for (int j2 = 0; j2 < 8; ++j2) {
      f4v dp = *(const f4v*)&sh_dp[4*j2];
      half2_t ha0 = bch(hpr0[2*j2]), hb0 = bch(hpr0[2*j2+1]);
      half2_t ha1 = bch(hpr1[2*j2]), hb1 = bch(hpr1[2*j2+1]);
      float v0 = v_d[4*j2], v1 = v_d[4*j2+1], v2 = v_d[4*j2+2], v3 = v_d[4*j2+3];
      rs0 = fmaf(v0, frcp(1.0f + fexp2(dp.x + (float)ha0.x)), rs0);
      rs0 = fmaf(v1, frcp(1.0f + fexp2(dp.y + (float)ha0.y)), rs0);
      rs0 = fmaf(v2, frcp(1.0f + fexp2(dp.z + (float)hb0.x)), rs0);
      rs0 = fmaf(v3, frcp(1.0f + fexp2(dp.w + (float)hb0.y)), rs0);
      rs1 = fmaf(v0, frcp(1.0f + fexp2(dp.x + (float)ha1.x)), rs1);
      rs1 = fmaf(v1, frcp(1.0f + fexp2(dp.y + (float)ha1.y)), rs1);
      rs1 = fmaf(v2, frcp(1.0f + fexp2(dp.z + (float)hb1.x)), rs1);
      rs1 = fmaf(v3, frcp(1.0f + fexp2(dp.w + (float)hb1.y)), rs1);
    }
    float e0 = fexp2(fmaf(-C2, rs0, c1));
    float e1 = fexp2(fmaf(-C2, rs1, c1));
    // three interleaved wave reductions
    float p0 = e0 + e1;
    float p1 = fmaf(e0, hw0, e1 * hw1);
    float p2 = wout1 * dnew;
    #pragma unroll
    for (int off = 32; off > 0; off >>= 1) {
      p0 += __shfl_xor(p0, off);
      p1 += __shfl_xor(p1, off);
      p2 += __shfl_xor(p2, off);
    }
    float o = fmaf(p1, frcp(p0), p2 + bo);
    if (l == 0) out[(size_t)b * HOR + s] = o;
    oprev = o;
  }
}

extern "C" void kernel_launch(void* const* d_in, const int* in_sizes, int n_in,
                              void* d_out, int out_size, void* d_ws, size_t ws_size,
                              hipStream_t stream) {
  const float* x      = (const float*)d_in[0];
  const float* W_ih_e = (const float*)d_in[1];
  const float* W_hh_e = (const float*)d_in[2];
  const float* b_ih_e = (const float*)d_in[3];
  const float* b_hh_e = (const float*)d_in[4];
  // d_in[5..8] = W_e, U_e, b_e, v_e : dead (softmax over size-1 axis == 1)
  const float* W_init = (const float*)d_in[9];
  const float* b_init = (const float*)d_in[10];
  const float* W_ih_d = (const float*)d_in[11];
  const float* W_hh_d = (const float*)d_in[12];
  const float* b_ih_d = (const float*)d_in[13];
  const float* b_hh_d = (const float*)d_in[14];
  const float* W_d    = (const float*)d_in[15];
  const float* U_d    = (const float*)d_in[16];
  const float* v_d    = (const float*)d_in[17];
  const float* W_out  = (const float*)d_in[18];
  const float* b_out  = (const float*)d_in[19];
  const float* y0     = (const float*)d_in[20];
  float* outp = (float*)d_out;

  darnn_kernel<<<BATCH, 64, 0, stream>>>(x, W_ih_e, W_hh_e, b_ih_e, b_hh_e,
      W_init, b_init, W_ih_d, W_hh_d, b_ih_d, b_hh_d, W_d, U_d, v_d, W_out,
      b_out, y0, outp);
}

// Round 6
// 446.270 us; speedup vs baseline: 1.7521x; 1.7521x over previous
//
#include <hip/hip_runtime.h>
#include <math.h>

#define BATCH 4096
#define T 128
#define HOR 24
#define HPS 17                     // sh_hp stride (odd -> conflict-free columns)

#define LOG2E 1.44269504088896f
#define C2    2.88539008177793f   // 2*log2(e)

typedef _Float16 half2_t __attribute__((ext_vector_type(2)));
typedef float f2  __attribute__((ext_vector_type(2)));
typedef float f4v __attribute__((ext_vector_type(4)));

__device__ __forceinline__ float fexp2(float x){ return __builtin_amdgcn_exp2f(x); }
__device__ __forceinline__ float frcp(float x){ return __builtin_amdgcn_rcpf(x); }
__device__ __forceinline__ float fsig(float x){ return frcp(1.0f + fexp2(-LOG2E*x)); }
__device__ __forceinline__ float ftanh(float x){ return fmaf(-2.0f, frcp(1.0f + fexp2(C2*x)), 1.0f); }
__device__ __forceinline__ half2_t bch(unsigned u){ return __builtin_bit_cast(half2_t,u); }
__device__ __forceinline__ unsigned pk2(float a,float b){ return __builtin_bit_cast(unsigned, __builtin_amdgcn_cvt_pkrtz(a,b)); }
__device__ __forceinline__ float fdot2f(half2_t a, half2_t b, float c){
#if __has_builtin(__builtin_amdgcn_fdot2)
  return __builtin_amdgcn_fdot2(a,b,c,false);
#else
  return fmaf((float)a.x,(float)b.x, fmaf((float)a.y,(float)b.y,c));
#endif
}
__device__ __forceinline__ f2 pkfma(f2 a, f2 b, f2 c){ return __builtin_elementwise_fma(a,b,c); }

// One wave per batch element (blockDim=64). Wave-synchronous: DS ops from a
// single wave execute in order -> ZERO barriers in the whole kernel.
// Lane l owns h[l]/d[l]; GRU rows l,64+l,128+l packed fp16 in VGPRs.
// __launch_bounds__(64,2): 256-reg unified budget. DO NOT raise to 3 —
// at 168 regs the allocator spills the weight arrays to scratch and
// FETCH_SIZE explodes ~80x (R5 post-mortem: 505 -> 782 us).
__global__ __launch_bounds__(64, 2)
void darnn_kernel(const float* __restrict__ x,
                  const float* __restrict__ W_ih_e, const float* __restrict__ W_hh_e,
                  const float* __restrict__ b_ih_e, const float* __restrict__ b_hh_e,
                  const float* __restrict__ W_init, const float* __restrict__ b_init,
                  const float* __restrict__ W_ih_d, const float* __restrict__ W_hh_d,
                  const float* __restrict__ b_ih_d, const float* __restrict__ b_hh_d,
                  const float* __restrict__ W_d, const float* __restrict__ U_d,
                  const float* __restrict__ v_d, const float* __restrict__ W_out,
                  const float* __restrict__ b_out, const float* __restrict__ y0,
                  float* __restrict__ out)
{
  const int l = threadIdx.x;            // 0..63
  const int b = blockIdx.x;
  const int a    = l & 31;
  const int half = l >> 5;

  __shared__ __align__(16) unsigned  sh_hp[T*HPS];  // 8704 B: cols 0..15 = Hp fp16x2 (pre-scaled C2), col 16 = hw[t] bits
  __shared__ __align__(16) float     sh_x[T];       // 512 B  (reused: [0..63] = h_T fp32 after encoder)
  __shared__ __align__(16) float     sh_dp[32];     // 128 B  d_proj (pre-scaled C2)
  __shared__ __align__(16) _Float16  sh_h16[64];    // 128 B  h (later d) fp16

  unsigned wr_r[32], wr_z[32], wr_n[32];  // GRU W_hh rows, fp16-packed (96 VGPR)
  unsigned udr[16];                        // U_d (later W_d) row a / half (16 VGPR)

  // ---------------- stage ----------------
  {
    const f4v* wp = (const f4v*)W_hh_e;
    #pragma unroll
    for (int k = 0; k < 16; ++k) {
      f4v vr = wp[l*16 + k];
      f4v vz = wp[(64 + l)*16 + k];
      f4v vn = wp[(128 + l)*16 + k];
      wr_r[2*k] = pk2(vr.x, vr.y); wr_r[2*k+1] = pk2(vr.z, vr.w);
      wr_z[2*k] = pk2(vz.x, vz.y); wr_z[2*k+1] = pk2(vz.z, vz.w);
      wr_n[2*k] = pk2(vn.x, vn.y); wr_n[2*k+1] = pk2(vn.z, vn.w);
    }
  }
  float wih0 = W_ih_e[l], wih1 = W_ih_e[64+l], wih2 = W_ih_e[128+l];
  float bb0  = b_ih_e[l] + b_hh_e[l];
  float bb1  = b_ih_e[64+l] + b_hh_e[64+l];
  float bih2 = b_ih_e[128+l], bhh2 = b_hh_e[128+l];
  float wo2l = W_out[64 + l];
  {
    f2 g = ((const f2*)(x + (size_t)b * T))[l];
    sh_x[2*l] = g.x; sh_x[2*l+1] = g.y;
  }
  sh_h16[l] = (_Float16)0.0f;
  {  // U_d row a, half `half` -> registers (lane only ever needs its own column)
    const f2* up = (const f2*)(U_d + a*64 + half*32);
    #pragma unroll
    for (int k = 0; k < 16; ++k) { f2 f = up[k]; udr[k] = pk2(f.x, f.y); }
  }

  // ---------------- encoder: 128 steps, wave-synchronous ----------------
  // input-attention is identity (softmax over size-1 axis == 1).
  float hprev = 0.0f;
  #pragma unroll 2
  for (int t = 0; t < T; ++t) {
    // all three gates share one pass over h16 (8 uint4 broadcast reads)
    float ar0=0.f, ar1=0.f, az0=0.f, az1=0.f, an0=0.f, an1=0.f;
    {
      const uint4* hq = (const uint4*)sh_h16;
      #pragma unroll
      for (int q = 0; q < 8; ++q) {
        uint4 hv = hq[q];
        ar0 = fdot2f(bch(hv.x), bch(wr_r[4*q+0]), ar0);
        az0 = fdot2f(bch(hv.x), bch(wr_z[4*q+0]), az0);
        an0 = fdot2f(bch(hv.x), bch(wr_n[4*q+0]), an0);
        ar1 = fdot2f(bch(hv.y), bch(wr_r[4*q+1]), ar1);
        az1 = fdot2f(bch(hv.y), bch(wr_z[4*q+1]), az1);
        an1 = fdot2f(bch(hv.y), bch(wr_n[4*q+1]), an1);
        ar0 = fdot2f(bch(hv.z), bch(wr_r[4*q+2]), ar0);
        az0 = fdot2f(bch(hv.z), bch(wr_z[4*q+2]), az0);
        an0 = fdot2f(bch(hv.z), bch(wr_n[4*q+2]), an0);
        ar1 = fdot2f(bch(hv.w), bch(wr_r[4*q+3]), ar1);
        az1 = fdot2f(bch(hv.w), bch(wr_z[4*q+3]), az1);
        an1 = fdot2f(bch(hv.w), bch(wr_n[4*q+3]), an1);
      }
    }
    float xt = sh_x[t];
    float r = fsig(fmaf(xt, wih0, bb0) + ar0 + ar1);
    float z = fsig(fmaf(xt, wih1, bb1) + az0 + az1);
    float n = ftanh(fmaf(xt, wih2, bih2) + r * (an0 + an1 + bhh2));
    float hnew = fmaf(z, hprev - n, n);
    hprev = hnew;
    sh_h16[l] = (_Float16)hnew;          // DS in-order: later reads see this
    // Hp[t][a] (pre-scaled by C2, fp16-packed)
    {
      float acc = 0.f;
      const uint4* hb16 = (const uint4*)(sh_h16 + 32*half);
      #pragma unroll
      for (int kk = 0; kk < 4; ++kk) {
        uint4 hv = hb16[kk];
        acc = fdot2f(bch(hv.x), bch(udr[4*kk+0]), acc);
        acc = fdot2f(bch(hv.y), bch(udr[4*kk+1]), acc);
        acc = fdot2f(bch(hv.z), bch(udr[4*kk+2]), acc);
        acc = fdot2f(bch(hv.w), bch(udr[4*kk+3]), acc);
      }
      acc += __shfl_xor(acc, 32);        // combine halves -> lanes 0..31 hold a
      acc *= C2;
      float accn = __shfl_down(acc, 1);
      if (l < 32 && !(l & 1))
        sh_hp[t*HPS + (l >> 1)] = pk2(acc, accn);
    }
    // hw[t] = W_out2 . h_t  -> sh_hp col 16
    {
      float p = wo2l * hnew;
      #pragma unroll
      for (int o = 32; o > 0; o >>= 1) p += __shfl_xor(p, o);
      if (l == 0) sh_hp[t*HPS + 16] = __builtin_bit_cast(unsigned, p);
    }
  }

  // ---------------- decoder prep ----------------
  sh_x[l] = hprev;                       // h_T fp32 (sh_x free after encoder)
  float dprev;
  {  // d0 = h_T @ W_init.T + b_init  (fp32 packed fma)
    const f4v* wi = (const f4v*)(W_init + l*64);
    const f4v* hb = (const f4v*)sh_x;
    f2 a0 = {0.f,0.f}, a1 = {0.f,0.f};
    #pragma unroll
    for (int k = 0; k < 16; ++k) {
      f4v wv = wi[k]; f4v hv = hb[k];
      a0 = pkfma(wv.xy, hv.xy, a0);
      a1 = pkfma(wv.zw, hv.zw, a1);
    }
    dprev = b_init[l] + (a0.x + a0.y) + (a1.x + a1.y);
  }
  {  // reload GRU weights with decoder W_hh
    const f4v* wp = (const f4v*)W_hh_d;
    #pragma unroll
    for (int k = 0; k < 16; ++k) {
      f4v vr = wp[l*16 + k];
      f4v vz = wp[(64 + l)*16 + k];
      f4v vn = wp[(128 + l)*16 + k];
      wr_r[2*k] = pk2(vr.x, vr.y); wr_r[2*k+1] = pk2(vr.z, vr.w);
      wr_z[2*k] = pk2(vz.x, vz.y); wr_z[2*k+1] = pk2(vz.z, vz.w);
      wr_n[2*k] = pk2(vn.x, vn.y); wr_n[2*k+1] = pk2(vn.z, vn.w);
    }
  }
  wih0 = W_ih_d[l]; wih1 = W_ih_d[64+l]; wih2 = W_ih_d[128+l];
  bb0  = b_ih_d[l] + b_hh_d[l];
  bb1  = b_ih_d[64+l] + b_hh_d[64+l];
  bih2 = b_ih_d[128+l]; bhh2 = b_hh_d[128+l];
  {  // W_d row -> udr (overwrites U_d row)
    const f2* up = (const f2*)(W_d + a*64 + half*32);
    #pragma unroll
    for (int k = 0; k < 16; ++k) { f2 f = up[k]; udr[k] = pk2(f.x, f.y); }
  }
  float wout1 = W_out[l];
  float hw0 = __builtin_bit_cast(float, sh_hp[l*HPS + 16]);
  float hw1 = __builtin_bit_cast(float, sh_hp[(64 + l)*HPS + 16]);
  float oprev = y0[0];
  float bo = b_out[0];
  float c1;                              // log2e * sum(v_d)
  {
    float sv = v_d[a];
    sv += __shfl_xor(sv, 16); sv += __shfl_xor(sv, 8);
    sv += __shfl_xor(sv, 4);  sv += __shfl_xor(sv, 2); sv += __shfl_xor(sv, 1);
    c1 = LOG2E * sv;
  }
  sh_h16[l] = (_Float16)dprev;

  const unsigned* hpr0 = sh_hp + l*HPS;
  const unsigned* hpr1 = sh_hp + (64 + l)*HPS;

  // ---------------- decoder: 24 steps, wave-synchronous ----------------
  for (int s = 0; s < HOR; ++s) {
    // GRU matvec (shared h16 pass) + combine
    float ar0=0.f, ar1=0.f, az0=0.f, az1=0.f, an0=0.f, an1=0.f;
    {
      const uint4* hq = (const uint4*)sh_h16;
      #pragma unroll
      for (int q = 0; q < 8; ++q) {
        uint4 hv = hq[q];
        ar0 = fdot2f(bch(hv.x), bch(wr_r[4*q+0]), ar0);
        az0 = fdot2f(bch(hv.x), bch(wr_z[4*q+0]), az0);
        an0 = fdot2f(bch(hv.x), bch(wr_n[4*q+0]), an0);
        ar1 = fdot2f(bch(hv.y), bch(wr_r[4*q+1]), ar1);
        az1 = fdot2f(bch(hv.y), bch(wr_z[4*q+1]), az1);
        an1 = fdot2f(bch(hv.y), bch(wr_n[4*q+1]), an1);
        ar0 = fdot2f(bch(hv.z), bch(wr_r[4*q+2]), ar0);
        az0 = fdot2f(bch(hv.z), bch(wr_z[4*q+2]), az0);
        an0 = fdot2f(bch(hv.z), bch(wr_n[4*q+2]), an0);
        ar1 = fdot2f(bch(hv.w), bch(wr_r[4*q+3]), ar1);
        az1 = fdot2f(bch(hv.w), bch(wr_z[4*q+3]), az1);
        an1 = fdot2f(bch(hv.w), bch(wr_n[4*q+3]), an1);
      }
    }
    float r = fsig(fmaf(oprev, wih0, bb0) + ar0 + ar1);
    float z = fsig(fmaf(oprev, wih1, bb1) + az0 + az1);
    float n = ftanh(fmaf(oprev, wih2, bih2) + r * (an0 + an1 + bhh2));
    float dnew = fmaf(z, dprev - n, n);
    dprev = dnew;
    sh_h16[l] = (_Float16)dnew;
    // d_proj[a] (pre-scaled C2) -> sh_dp
    {
      float acc = 0.f;
      const uint4* db16 = (const uint4*)(sh_h16 + 32*half);
      #pragma unroll
      for (int kk = 0; kk < 4; ++kk) {
        uint4 dv = db16[kk];
        acc = fdot2f(bch(dv.x), bch(udr[4*kk+0]), acc);
        acc = fdot2f(bch(dv.y), bch(udr[4*kk+1]), acc);
        acc = fdot2f(bch(dv.z), bch(udr[4*kk+2]), acc);
        acc = fdot2f(bch(dv.w), bch(udr[4*kk+3]), acc);
      }
      acc += __shfl_xor(acc, 32);
      if (l < 32) sh_dp[l] = C2 * acc;
    }
    // scores rows t0=l, t1=64+l: score = SV - 2*sum_a v_a*sig2(dps+hps)
    float rs0 = 0.f, rs1 = 0.f;
    #pragma unroll
    for (int j2 = 0; j2 < 8; ++j2) {
      f4v dp = *(const f4v*)&sh_dp[4*j2];
      half2_t ha0 = bch(hpr0[2*j2]), hb0 = bch(hpr0[2*j2+1]);
      half2_t ha1 = bch(hpr1[2*j2]), hb1 = bch(hpr1[2*j2+1]);
      float v0 = v_d[4*j2], v1 = v_d[4*j2+1], v2 = v_d[4*j2+2], v3 = v_d[4*j2+3];
      rs0 = fmaf(v0, frcp(1.0f + fexp2(dp.x + (float)ha0.x)), rs0);
      rs0 = fmaf(v1, frcp(1.0f + fexp2(dp.y + (float)ha0.y)), rs0);
      rs0 = fmaf(v2, frcp(1.0f + fexp2(dp.z + (float)hb0.x)), rs0);
      rs0 = fmaf(v3, frcp(1.0f + fexp2(dp.w + (float)hb0.y)), rs0);
      rs1 = fmaf(v0, frcp(1.0f + fexp2(dp.x + (float)ha1.x)), rs1);
      rs1 = fmaf(v1, frcp(1.0f + fexp2(dp.y + (float)ha1.y)), rs1);
      rs1 = fmaf(v2, frcp(1.0f + fexp2(dp.z + (float)hb1.x)), rs1);
      rs1 = fmaf(v3, frcp(1.0f + fexp2(dp.w + (float)hb1.y)), rs1);
    }
    float e0 = fexp2(fmaf(-C2, rs0, c1));
    float e1 = fexp2(fmaf(-C2, rs1, c1));
    // three interleaved wave reductions
    float p0 = e0 + e1;
    float p1 = fmaf(e0, hw0, e1 * hw1);
    float p2 = wout1 * dnew;
    #pragma unroll
    for (int off = 32; off > 0; off >>= 1) {
      p0 += __shfl_xor(p0, off);
      p1 += __shfl_xor(p1, off);
      p2 += __shfl_xor(p2, off);
    }
    float o = fmaf(p1, frcp(p0), p2 + bo);
    if (l == 0) out[(size_t)b * HOR + s] = o;
    oprev = o;
  }
}

extern "C" void kernel_launch(void* const* d_in, const int* in_sizes, int n_in,
                              void* d_out, int out_size, void* d_ws, size_t ws_size,
                              hipStream_t stream) {
  const float* x      = (const float*)d_in[0];
  const float* W_ih_e = (const float*)d_in[1];
  const float* W_hh_e = (const float*)d_in[2];
  const float* b_ih_e = (const float*)d_in[3];
  const float* b_hh_e = (const float*)d_in[4];
  // d_in[5..8] = W_e, U_e, b_e, v_e : dead (softmax over size-1 axis == 1)
  const float* W_init = (const float*)d_in[9];
  const float* b_init = (const float*)d_in[10];
  const float* W_ih_d = (const float*)d_in[11];
  const float* W_hh_d = (const float*)d_in[12];
  const float* b_ih_d = (const float*)d_in[13];
  const float* b_hh_d = (const float*)d_in[14];
  const float* W_d    = (const float*)d_in[15];
  const float* U_d    = (const float*)d_in[16];
  const float* v_d    = (const float*)d_in[17];
  const float* W_out  = (const float*)d_in[18];
  const float* b_out  = (const float*)d_in[19];
  const float* y0     = (const float*)d_in[20];
  float* outp = (float*)d_out;

  darnn_kernel<<<BATCH, 64, 0, stream>>>(x, W_ih_e, W_hh_e, b_ih_e, b_hh_e,
      W_init, b_init, W_ih_d, W_hh_d, b_ih_d, b_hh_d, W_d, U_d, v_d, W_out,
      b_out, y0, outp);
}

// Round 7
// 406.471 us; speedup vs baseline: 1.9236x; 1.0979x over previous
//
#include <hip/hip_runtime.h>
#include <math.h>

#define BATCH 4096
#define T 128
#define HOR 24
#define HPS 17                     // sh_hp stride (odd -> conflict-free columns)

#define LOG2E 1.44269504088896f
#define C2    2.88539008177793f   // 2*log2(e)

typedef _Float16 half2_t __attribute__((ext_vector_type(2)));
typedef float f2  __attribute__((ext_vector_type(2)));
typedef float f4v __attribute__((ext_vector_type(4)));

__device__ __forceinline__ float fexp2(float x){ return __builtin_amdgcn_exp2f(x); }
__device__ __forceinline__ float frcp(float x){ return __builtin_amdgcn_rcpf(x); }
__device__ __forceinline__ float fsig(float x){ return frcp(1.0f + fexp2(-LOG2E*x)); }
__device__ __forceinline__ float ftanh(float x){ return fmaf(-2.0f, frcp(1.0f + fexp2(C2*x)), 1.0f); }
__device__ __forceinline__ half2_t bch(unsigned u){ return __builtin_bit_cast(half2_t,u); }
__device__ __forceinline__ unsigned pk2(float a,float b){ return __builtin_bit_cast(unsigned, __builtin_amdgcn_cvt_pkrtz(a,b)); }
__device__ __forceinline__ float fdot2f(half2_t a, half2_t b, float c){
#if __has_builtin(__builtin_amdgcn_fdot2)
  return __builtin_amdgcn_fdot2(a,b,c,false);
#else
  return fmaf((float)a.x,(float)b.x, fmaf((float)a.y,(float)b.y,c));
#endif
}
__device__ __forceinline__ f2 pkfma(f2 a, f2 b, f2 c){ return __builtin_elementwise_fma(a,b,c); }

// One wave per batch element (blockDim=64). Wave-synchronous: DS ops from a
// single wave execute in order -> ZERO barriers. Lane l owns h[l]/d[l];
// GRU rows l,64+l,128+l packed fp16 in VGPRs (96 regs).
// __launch_bounds__(64,2): 256-reg budget. DO NOT raise to 3 — spills
// weight arrays to scratch, FETCH explodes 80x (R5: 505 -> 782 us).
// h lives in an 8-row fp16 ring so Hp/hw tails are BATCHED every 8 steps
// (R6 did them per-step: 8 dependent LDS-pipe shuffles/step = ~500 stall
// cycles/step; batching cuts shuffle count 8-16x).
__global__ __launch_bounds__(64, 2)
void darnn_kernel(const float* __restrict__ x,
                  const float* __restrict__ W_ih_e, const float* __restrict__ W_hh_e,
                  const float* __restrict__ b_ih_e, const float* __restrict__ b_hh_e,
                  const float* __restrict__ W_init, const float* __restrict__ b_init,
                  const float* __restrict__ W_ih_d, const float* __restrict__ W_hh_d,
                  const float* __restrict__ b_ih_d, const float* __restrict__ b_hh_d,
                  const float* __restrict__ W_d, const float* __restrict__ U_d,
                  const float* __restrict__ v_d, const float* __restrict__ W_out,
                  const float* __restrict__ b_out, const float* __restrict__ y0,
                  float* __restrict__ out)
{
  const int l = threadIdx.x;            // 0..63
  const int b = blockIdx.x;
  const int a    = l & 31;
  const int half = l >> 5;

  __shared__ __align__(16) unsigned  sh_hp[T*HPS];   // 8704 B: cols 0..15 Hp fp16x2 (pre-scaled C2), col 16 hw[t]
  __shared__ __align__(16) _Float16  sh_ring[8*72];  // 1152 B: h ring, row stride 72 (144B, 16B-aligned)
  __shared__ __align__(16) float     sh_x[T];        // 512 B (reused: [0..63] = h_T fp32)
  __shared__ __align__(16) float     sh_dp[32];      // 128 B d_proj (pre-scaled C2)
  __shared__ __align__(16) float     sh_wo2f[64];    // 256 B W_out[64..127] fp32

  unsigned wr_r[32], wr_z[32], wr_n[32];  // GRU W_hh rows fp16-packed (96 VGPR)
  unsigned udr[16];                        // U_d (later W_d) row a, half `half`

  // ---------------- stage ----------------
  {
    const f4v* wp = (const f4v*)W_hh_e;
    #pragma unroll
    for (int k = 0; k < 16; ++k) {
      f4v vr = wp[l*16 + k];
      f4v vz = wp[(64 + l)*16 + k];
      f4v vn = wp[(128 + l)*16 + k];
      wr_r[2*k] = pk2(vr.x, vr.y); wr_r[2*k+1] = pk2(vr.z, vr.w);
      wr_z[2*k] = pk2(vz.x, vz.y); wr_z[2*k+1] = pk2(vz.z, vz.w);
      wr_n[2*k] = pk2(vn.x, vn.y); wr_n[2*k+1] = pk2(vn.z, vn.w);
    }
  }
  float wih0 = W_ih_e[l], wih1 = W_ih_e[64+l], wih2 = W_ih_e[128+l];
  float bb0  = b_ih_e[l] + b_hh_e[l];
  float bb1  = b_ih_e[64+l] + b_hh_e[64+l];
  float bih2 = b_ih_e[128+l], bhh2 = b_hh_e[128+l];
  sh_wo2f[l] = W_out[64 + l];
  {
    f2 g = ((const f2*)(x + (size_t)b * T))[l];
    sh_x[2*l] = g.x; sh_x[2*l+1] = g.y;
  }
  sh_ring[7*72 + l] = (_Float16)0.0f;    // h_{-1} = 0 (step 0 reads row 7)
  {  // U_d row a, half -> registers
    const f2* up = (const f2*)(U_d + a*64 + half*32);
    #pragma unroll
    for (int k = 0; k < 16; ++k) { f2 f = up[k]; udr[k] = pk2(f.x, f.y); }
  }

  // ---------------- encoder: 128 steps, wave-synchronous ----------------
  // input-attention is identity (softmax over size-1 axis == 1).
  float hprev = 0.0f;
  for (int t0 = 0; t0 < T; t0 += 8) {
    #pragma unroll
    for (int u = 0; u < 8; ++u) {
      const int t = t0 + u;
      float ar0=0.f, ar1=0.f, az0=0.f, az1=0.f, an0=0.f, an1=0.f;
      {
        const uint4* hq = (const uint4*)(sh_ring + ((t+7)&7)*72);
        #pragma unroll
        for (int q = 0; q < 8; ++q) {
          uint4 hv = hq[q];
          ar0 = fdot2f(bch(hv.x), bch(wr_r[4*q+0]), ar0);
          az0 = fdot2f(bch(hv.x), bch(wr_z[4*q+0]), az0);
          an0 = fdot2f(bch(hv.x), bch(wr_n[4*q+0]), an0);
          ar1 = fdot2f(bch(hv.y), bch(wr_r[4*q+1]), ar1);
          az1 = fdot2f(bch(hv.y), bch(wr_z[4*q+1]), az1);
          an1 = fdot2f(bch(hv.y), bch(wr_n[4*q+1]), an1);
          ar0 = fdot2f(bch(hv.z), bch(wr_r[4*q+2]), ar0);
          az0 = fdot2f(bch(hv.z), bch(wr_z[4*q+2]), az0);
          an0 = fdot2f(bch(hv.z), bch(wr_n[4*q+2]), an0);
          ar1 = fdot2f(bch(hv.w), bch(wr_r[4*q+3]), ar1);
          az1 = fdot2f(bch(hv.w), bch(wr_z[4*q+3]), az1);
          an1 = fdot2f(bch(hv.w), bch(wr_n[4*q+3]), an1);
        }
      }
      float xt = sh_x[t];
      float r = fsig(fmaf(xt, wih0, bb0) + ar0 + ar1);
      float z = fsig(fmaf(xt, wih1, bb1) + az0 + az1);
      float n = ftanh(fmaf(xt, wih2, bih2) + r * (an0 + an1 + bhh2));
      float hnew = fmaf(z, hprev - n, n);
      hprev = hnew;
      sh_ring[(t&7)*72 + l] = (_Float16)hnew;
    }
    // ---- Hp batch for t0..t0+7: lane (a, half), 16 dot2 per t ----
    #pragma unroll
    for (int k = 0; k < 8; ++k) {
      float acc = 0.f;
      const uint4* hb = (const uint4*)(sh_ring + k*72 + half*32);
      #pragma unroll
      for (int q = 0; q < 4; ++q) {
        uint4 hv = hb[q];
        acc = fdot2f(bch(hv.x), bch(udr[4*q+0]), acc);
        acc = fdot2f(bch(hv.y), bch(udr[4*q+1]), acc);
        acc = fdot2f(bch(hv.z), bch(udr[4*q+2]), acc);
        acc = fdot2f(bch(hv.w), bch(udr[4*q+3]), acc);
      }
      acc += __shfl_xor(acc, 32);          // combine halves
      acc *= C2;
      float accn = __shfl_down(acc, 1);    // neighbor a+1 (same half)
      if (l < 32 && !(l & 1))
        sh_hp[(t0+k)*HPS + (l >> 1)] = pk2(acc, accn);
    }
    // ---- hw batch for t0..t0+7 (fp32): lane (r8=t, c8=8-dim chunk) ----
    {
      int r8 = l >> 3, c8 = l & 7;
      uint4 hv = *(const uint4*)(sh_ring + r8*72 + c8*8);
      const f4v* w4 = (const f4v*)&sh_wo2f[c8*8];
      f4v wa = w4[0], wb = w4[1];
      half2_t h0 = bch(hv.x), h1 = bch(hv.y), h2 = bch(hv.z), h3 = bch(hv.w);
      float p;
      p = (float)h0.x*wa.x;
      p = fmaf((float)h0.y, wa.y, p);
      p = fmaf((float)h1.x, wa.z, p);
      p = fmaf((float)h1.y, wa.w, p);
      p = fmaf((float)h2.x, wb.x, p);
      p = fmaf((float)h2.y, wb.y, p);
      p = fmaf((float)h3.x, wb.z, p);
      p = fmaf((float)h3.y, wb.w, p);
      p += __shfl_xor(p, 1);
      p += __shfl_xor(p, 2);
      p += __shfl_xor(p, 4);
      if (c8 == 0) sh_hp[(t0+r8)*HPS + 16] = __builtin_bit_cast(unsigned, p);
    }
  }

  // ---------------- decoder prep ----------------
  sh_x[l] = hprev;                       // h_T fp32 stash
  float dprev;
  {  // d0 = h_T @ W_init.T + b_init (fp32 packed fma)
    const f4v* wi = (const f4v*)(W_init + l*64);
    const f4v* hb = (const f4v*)sh_x;
    f2 a0 = {0.f,0.f}, a1 = {0.f,0.f};
    #pragma unroll
    for (int k = 0; k < 16; ++k) {
      f4v wv = wi[k]; f4v hv = hb[k];
      a0 = pkfma(wv.xy, hv.xy, a0);
      a1 = pkfma(wv.zw, hv.zw, a1);
    }
    dprev = b_init[l] + (a0.x + a0.y) + (a1.x + a1.y);
  }
  {  // reload GRU weights with decoder W_hh
    const f4v* wp = (const f4v*)W_hh_d;
    #pragma unroll
    for (int k = 0; k < 16; ++k) {
      f4v vr = wp[l*16 + k];
      f4v vz = wp[(64 + l)*16 + k];
      f4v vn = wp[(128 + l)*16 + k];
      wr_r[2*k] = pk2(vr.x, vr.y); wr_r[2*k+1] = pk2(vr.z, vr.w);
      wr_z[2*k] = pk2(vz.x, vz.y); wr_z[2*k+1] = pk2(vz.z, vz.w);
      wr_n[2*k] = pk2(vn.x, vn.y); wr_n[2*k+1] = pk2(vn.z, vn.w);
    }
  }
  wih0 = W_ih_d[l]; wih1 = W_ih_d[64+l]; wih2 = W_ih_d[128+l];
  bb0  = b_ih_d[l] + b_hh_d[l];
  bb1  = b_ih_d[64+l] + b_hh_d[64+l];
  bih2 = b_ih_d[128+l]; bhh2 = b_hh_d[128+l];
  {  // W_d row -> udr (overwrites U_d row)
    const f2* up = (const f2*)(W_d + a*64 + half*32);
    #pragma unroll
    for (int k = 0; k < 16; ++k) { f2 f = up[k]; udr[k] = pk2(f.x, f.y); }
  }
  float wout1 = W_out[l];
  float hw0 = __builtin_bit_cast(float, sh_hp[l*HPS + 16]);
  float hw1 = __builtin_bit_cast(float, sh_hp[(64 + l)*HPS + 16]);
  float oprev = y0[0];
  float bo = b_out[0];
  float c1;                              // log2e * sum(v_d)
  {
    float sv = v_d[a];
    sv += __shfl_xor(sv, 16); sv += __shfl_xor(sv, 8);
    sv += __shfl_xor(sv, 4);  sv += __shfl_xor(sv, 2); sv += __shfl_xor(sv, 1);
    c1 = LOG2E * sv;
  }
  sh_ring[l] = (_Float16)dprev;          // d fp16 lives in ring row 0

  const unsigned* hpr0 = sh_hp + l*HPS;
  const unsigned* hpr1 = sh_hp + (64 + l)*HPS;

  // ---------------- decoder: 24 steps, wave-synchronous ----------------
  for (int s = 0; s < HOR; ++s) {
    float ar0=0.f, ar1=0.f, az0=0.f, az1=0.f, an0=0.f, an1=0.f;
    {
      const uint4* hq = (const uint4*)sh_ring;   // row 0 = d fp16
      #pragma unroll
      for (int q = 0; q < 8; ++q) {
        uint4 hv = hq[q];
        ar0 = fdot2f(bch(hv.x), bch(wr_r[4*q+0]), ar0);
        az0 = fdot2f(bch(hv.x), bch(wr_z[4*q+0]), az0);
        an0 = fdot2f(bch(hv.x), bch(wr_n[4*q+0]), an0);
        ar1 = fdot2f(bch(hv.y), bch(wr_r[4*q+1]), ar1);
        az1 = fdot2f(bch(hv.y), bch(wr_z[4*q+1]), az1);
        an1 = fdot2f(bch(hv.y), bch(wr_n[4*q+1]), an1);
        ar0 = fdot2f(bch(hv.z), bch(wr_r[4*q+2]), ar0);
        az0 = fdot2f(bch(hv.z), bch(wr_z[4*q+2]), az0);
        an0 = fdot2f(bch(hv.z), bch(wr_n[4*q+2]), an0);
        ar1 = fdot2f(bch(hv.w), bch(wr_r[4*q+3]), ar1);
        az1 = fdot2f(bch(hv.w), bch(wr_z[4*q+3]), az1);
        an1 = fdot2f(bch(hv.w), bch(wr_n[4*q+3]), an1);
      }
    }
    float r = fsig(fmaf(oprev, wih0, bb0) + ar0 + ar1);
    float z = fsig(fmaf(oprev, wih1, bb1) + az0 + az1);
    float n = ftanh(fmaf(oprev, wih2, bih2) + r * (an0 + an1 + bhh2));
    float dnew = fmaf(z, dprev - n, n);
    dprev = dnew;
    sh_ring[l] = (_Float16)dnew;
    // d_proj[a] (pre-scaled C2) -> sh_dp
    {
      float acc = 0.f;
      const uint4* db16 = (const uint4*)(sh_ring + 32*half);
      #pragma unroll
      for (int kk = 0; kk < 4; ++kk) {
        uint4 dv = db16[kk];
        acc = fdot2f(bch(dv.x), bch(udr[4*kk+0]), acc);
        acc = fdot2f(bch(dv.y), bch(udr[4*kk+1]), acc);
        acc = fdot2f(bch(dv.z), bch(udr[4*kk+2]), acc);
        acc = fdot2f(bch(dv.w), bch(udr[4*kk+3]), acc);
      }
      acc += __shfl_xor(acc, 32);
      if (l < 32) sh_dp[l] = C2 * acc;
    }
    // scores rows t0=l, t1=64+l: score = SV - 2*sum_a v_a*sig2(dps+hps)
    float rs0 = 0.f, rs1 = 0.f;
    #pragma unroll
    for (int j2 = 0; j2 < 8; ++j2) {
      f4v dp = *(const f4v*)&sh_dp[4*j2];
      half2_t ha0 = bch(hpr0[2*j2]), hb0 = bch(hpr0[2*j2+1]);
      half2_t ha1 = bch(hpr1[2*j2]), hb1 = bch(hpr1[2*j2+1]);
      float v0 = v_d[4*j2], v1 = v_d[4*j2+1], v2 = v_d[4*j2+2], v3 = v_d[4*j2+3];
      rs0 = fmaf(v0, frcp(1.0f + fexp2(dp.x + (float)ha0.x)), rs0);
      rs0 = fmaf(v1, frcp(1.0f + fexp2(dp.y + (float)ha0.y)), rs0);
      rs0 = fmaf(v2, frcp(1.0f + fexp2(dp.z + (float)hb0.x)), rs0);
      rs0 = fmaf(v3, frcp(1.0f + fexp2(dp.w + (float)hb0.y)), rs0);
      rs1 = fmaf(v0, frcp(1.0f + fexp2(dp.x + (float)ha1.x)), rs1);
      rs1 = fmaf(v1, frcp(1.0f + fexp2(dp.y + (float)ha1.y)), rs1);
      rs1 = fmaf(v2, frcp(1.0f + fexp2(dp.z + (float)hb1.x)), rs1);
      rs1 = fmaf(v3, frcp(1.0f + fexp2(dp.w + (float)hb1.y)), rs1);
    }
    float e0 = fexp2(fmaf(-C2, rs0, c1));
    float e1 = fexp2(fmaf(-C2, rs1, c1));
    // three interleaved wave reductions
    float p0 = e0 + e1;
    float p1 = fmaf(e0, hw0, e1 * hw1);
    float p2 = wout1 * dnew;
    #pragma unroll
    for (int off = 32; off > 0; off >>= 1) {
      p0 += __shfl_xor(p0, off);
      p1 += __shfl_xor(p1, off);
      p2 += __shfl_xor(p2, off);
    }
    float o = fmaf(p1, frcp(p0), p2 + bo);
    if (l == 0) out[(size_t)b * HOR + s] = o;
    oprev = o;
  }
}

extern "C" void kernel_launch(void* const* d_in, const int* in_sizes, int n_in,
                              void* d_out, int out_size, void* d_ws, size_t ws_size,
                              hipStream_t stream) {
  const float* x      = (const float*)d_in[0];
  const float* W_ih_e = (const float*)d_in[1];
  const float* W_hh_e = (const float*)d_in[2];
  const float* b_ih_e = (const float*)d_in[3];
  const float* b_hh_e = (const float*)d_in[4];
  // d_in[5..8] = W_e, U_e, b_e, v_e : dead (softmax over size-1 axis == 1)
  const float* W_init = (const float*)d_in[9];
  const float* b_init = (const float*)d_in[10];
  const float* W_ih_d = (const float*)d_in[11];
  const float* W_hh_d = (const float*)d_in[12];
  const float* b_ih_d = (const float*)d_in[13];
  const float* b_hh_d = (const float*)d_in[14];
  const float* W_d    = (const float*)d_in[15];
  const float* U_d    = (const float*)d_in[16];
  const float* v_d    = (const float*)d_in[17];
  const float* W_out  = (const float*)d_in[18];
  const float* b_out  = (const float*)d_in[19];
  const float* y0     = (const float*)d_in[20];
  float* outp = (float*)d_out;

  darnn_kernel<<<BATCH, 64, 0, stream>>>(x, W_ih_e, W_hh_e, b_ih_e, b_hh_e,
      W_init, b_init, W_ih_d, W_hh_d, b_ih_d, b_hh_d, W_d, U_d, v_d, W_out,
      b_out, y0, outp);
}

// Round 8
// 405.890 us; speedup vs baseline: 1.9264x; 1.0014x over previous
//
#include <hip/hip_runtime.h>
#include <math.h>

#define BATCH 4096
#define T 128
#define HOR 24
#define HPS 17                     // hp row stride in uint2 units

#define LOG2E 1.44269504088896f
#define C2    2.88539008177793f   // 2*log2(e)

typedef _Float16 half2_t __attribute__((ext_vector_type(2)));
typedef float f2  __attribute__((ext_vector_type(2)));
typedef float f4v __attribute__((ext_vector_type(4)));

__device__ __forceinline__ float fexp2(float x){ return __builtin_amdgcn_exp2f(x); }
__device__ __forceinline__ float frcp(float x){ return __builtin_amdgcn_rcpf(x); }
__device__ __forceinline__ float fsig(float x){ return frcp(1.0f + fexp2(-LOG2E*x)); }
__device__ __forceinline__ float ftanh(float x){ return fmaf(-2.0f, frcp(1.0f + fexp2(C2*x)), 1.0f); }
__device__ __forceinline__ half2_t bch(unsigned u){ return __builtin_bit_cast(half2_t,u); }
__device__ __forceinline__ unsigned pk2(float a,float b){ return __builtin_bit_cast(unsigned, __builtin_amdgcn_cvt_pkrtz(a,b)); }
__device__ __forceinline__ float fdot2f(half2_t a, half2_t b, float c){
#if __has_builtin(__builtin_amdgcn_fdot2)
  return __builtin_amdgcn_fdot2(a,b,c,false);
#else
  return fmaf((float)a.x,(float)b.x, fmaf((float)a.y,(float)b.y,c));
#endif
}
__device__ __forceinline__ f2 pkfma(f2 a, f2 b, f2 c){ return __builtin_elementwise_fma(a,b,c); }

__device__ __forceinline__ void gru_mv(const _Float16* hrow,
    const unsigned* wr_r, const unsigned* wr_z, const unsigned* wr_n,
    float& ar0, float& ar1, float& az0, float& az1, float& an0, float& an1)
{
  const uint4* hq = (const uint4*)hrow;      // broadcast reads (uniform addr)
  #pragma unroll
  for (int q = 0; q < 8; ++q) {
    uint4 hv = hq[q];
    ar0 = fdot2f(bch(hv.x), bch(wr_r[4*q+0]), ar0);
    az0 = fdot2f(bch(hv.x), bch(wr_z[4*q+0]), az0);
    an0 = fdot2f(bch(hv.x), bch(wr_n[4*q+0]), an0);
    ar1 = fdot2f(bch(hv.y), bch(wr_r[4*q+1]), ar1);
    az1 = fdot2f(bch(hv.y), bch(wr_z[4*q+1]), az1);
    an1 = fdot2f(bch(hv.y), bch(wr_n[4*q+1]), an1);
    ar0 = fdot2f(bch(hv.z), bch(wr_r[4*q+2]), ar0);
    az0 = fdot2f(bch(hv.z), bch(wr_z[4*q+2]), az0);
    an0 = fdot2f(bch(hv.z), bch(wr_n[4*q+2]), an0);
    ar1 = fdot2f(bch(hv.w), bch(wr_r[4*q+3]), ar1);
    az1 = fdot2f(bch(hv.w), bch(wr_z[4*q+3]), az1);
    an1 = fdot2f(bch(hv.w), bch(wr_n[4*q+3]), an1);
  }
}

__device__ __forceinline__ float proj_dot(const _Float16* base, const unsigned* udr)
{
  float acc = 0.f;
  const uint4* hb = (const uint4*)base;
  #pragma unroll
  for (int q = 0; q < 4; ++q) {
    uint4 hv = hb[q];
    acc = fdot2f(bch(hv.x), bch(udr[4*q+0]), acc);
    acc = fdot2f(bch(hv.y), bch(udr[4*q+1]), acc);
    acc = fdot2f(bch(hv.z), bch(udr[4*q+2]), acc);
    acc = fdot2f(bch(hv.w), bch(udr[4*q+3]), acc);
  }
  return acc;
}

// TWO batch elements per wave (blockDim=64, grid=BATCH/2). Weights (112 VGPR)
// are shared across elements; the second element costs only ~20 state regs but
// doubles in-wave ILP — the stall-filler that 2-waves/SIMD occupancy can't
// provide (R5: more waves => spill catastrophe). Wave-synchronous, ZERO
// barriers. LDS = 20224 B so all 8 blocks/CU are co-resident (one round).
// __launch_bounds__(64,2): 256-reg budget. DO NOT raise (R5: spills, 80x FETCH).
__global__ __launch_bounds__(64, 2)
void darnn_kernel(const float* __restrict__ x,
                  const float* __restrict__ W_ih_e, const float* __restrict__ W_hh_e,
                  const float* __restrict__ b_ih_e, const float* __restrict__ b_hh_e,
                  const float* __restrict__ W_init, const float* __restrict__ b_init,
                  const float* __restrict__ W_ih_d, const float* __restrict__ W_hh_d,
                  const float* __restrict__ b_ih_d, const float* __restrict__ b_hh_d,
                  const float* __restrict__ W_d, const float* __restrict__ U_d,
                  const float* __restrict__ v_d, const float* __restrict__ W_out,
                  const float* __restrict__ b_out, const float* __restrict__ y0,
                  float* __restrict__ out)
{
  const int l = threadIdx.x;            // 0..63
  const int b0 = 2*blockIdx.x, b1 = b0 + 1;
  const int a    = l & 31;
  const int half = l >> 5;

  // Manual LDS layout, 20224 B total (8 blocks x 20224 <= 160 KiB/CU):
  //   [0, 17408)     uint2 hp[T][17]: cols 0..15 = {elem0,elem1} Hp fp16x2
  //                  (pre-scaled C2); col 16 = {hw0,hw1} fp32 bits
  //   [17408, 19456) fp16 ring, 16 rows x 64: rows 0-7 elem0 h, 8-15 elem1 h
  //                  (decoder: row 0 = d0, row 8 = d1)
  //   [19456, 20224) phase union:
  //     encoder: x16_0[128] @19456, x16_1[128] @19712, wo2f[64] @19968
  //     prep:    hT0[64] @19456, hT1[64] @19712
  //     decoder: dp0[32] @19456, dp1[32] @19584
  __shared__ __align__(16) unsigned char smem[20224];
  uint2*    sh_hp   = (uint2*)smem;
  _Float16* sh_ring = (_Float16*)(smem + 17408);
  _Float16* sh_x0   = (_Float16*)(smem + 19456);
  _Float16* sh_x1   = (_Float16*)(smem + 19712);
  float*    sh_wo2f = (float*)(smem + 19968);
  float*    sh_hT0  = (float*)(smem + 19456);
  float*    sh_hT1  = (float*)(smem + 19712);
  float*    sh_dp0  = (float*)(smem + 19456);
  float*    sh_dp1  = (float*)(smem + 19584);

  unsigned wr_r[32], wr_z[32], wr_n[32];  // shared GRU W_hh rows fp16 (96 VGPR)
  unsigned udr[16];                        // shared U_d (later W_d) row a, half

  // ---------------- stage ----------------
  {
    const f4v* wp = (const f4v*)W_hh_e;
    #pragma unroll
    for (int k = 0; k < 16; ++k) {
      f4v vr = wp[l*16 + k];
      f4v vz = wp[(64 + l)*16 + k];
      f4v vn = wp[(128 + l)*16 + k];
      wr_r[2*k] = pk2(vr.x, vr.y); wr_r[2*k+1] = pk2(vr.z, vr.w);
      wr_z[2*k] = pk2(vz.x, vz.y); wr_z[2*k+1] = pk2(vz.z, vz.w);
      wr_n[2*k] = pk2(vn.x, vn.y); wr_n[2*k+1] = pk2(vn.z, vn.w);
    }
  }
  float wih0 = W_ih_e[l], wih1 = W_ih_e[64+l], wih2 = W_ih_e[128+l];
  float bb0  = b_ih_e[l] + b_hh_e[l];
  float bb1  = b_ih_e[64+l] + b_hh_e[64+l];
  float bih2 = b_ih_e[128+l], bhh2 = b_hh_e[128+l];
  sh_wo2f[l] = W_out[64 + l];
  {
    f2 g0 = ((const f2*)(x + (size_t)b0 * T))[l];
    f2 g1 = ((const f2*)(x + (size_t)b1 * T))[l];
    ((unsigned*)sh_x0)[l] = pk2(g0.x, g0.y);
    ((unsigned*)sh_x1)[l] = pk2(g1.x, g1.y);
  }
  sh_ring[7*64  + l] = (_Float16)0.0f;   // h_{-1} elem0
  sh_ring[15*64 + l] = (_Float16)0.0f;   // h_{-1} elem1
  {  // U_d row a, half -> registers
    const f2* up = (const f2*)(U_d + a*64 + half*32);
    #pragma unroll
    for (int k = 0; k < 16; ++k) { f2 f = up[k]; udr[k] = pk2(f.x, f.y); }
  }

  // ---------------- encoder: 128 steps, both elements ----------------
  // input-attention is identity (softmax over size-1 axis == 1).
  float hprev0 = 0.0f, hprev1 = 0.0f;
  #pragma unroll 1
  for (int t0 = 0; t0 < T; t0 += 8) {
    #pragma unroll
    for (int u = 0; u < 8; ++u) {
      const int t = t0 + u;
      float ar0=0,ar1=0,az0=0,az1=0,an0=0,an1=0;
      float br0=0,br1=0,bz0=0,bz1=0,bn0=0,bn1=0;
      gru_mv(sh_ring + ((t+7)&7)*64,      wr_r, wr_z, wr_n, ar0,ar1,az0,az1,an0,an1);
      gru_mv(sh_ring + (8+((t+7)&7))*64,  wr_r, wr_z, wr_n, br0,br1,bz0,bz1,bn0,bn1);
      float xt0 = (float)sh_x0[t], xt1 = (float)sh_x1[t];
      float r0 = fsig(fmaf(xt0, wih0, bb0) + ar0 + ar1);
      float r1 = fsig(fmaf(xt1, wih0, bb0) + br0 + br1);
      float z0 = fsig(fmaf(xt0, wih1, bb1) + az0 + az1);
      float z1 = fsig(fmaf(xt1, wih1, bb1) + bz0 + bz1);
      float n0 = ftanh(fmaf(xt0, wih2, bih2) + r0 * (an0 + an1 + bhh2));
      float n1 = ftanh(fmaf(xt1, wih2, bih2) + r1 * (bn0 + bn1 + bhh2));
      hprev0 = fmaf(z0, hprev0 - n0, n0);
      hprev1 = fmaf(z1, hprev1 - n1, n1);
      sh_ring[(t&7)*64 + l]     = (_Float16)hprev0;
      sh_ring[(8+(t&7))*64 + l] = (_Float16)hprev1;
    }
    // ---- Hp batch for t0..t0+7, both elements ----
    #pragma unroll
    for (int k = 0; k < 8; ++k) {
      float acc0 = proj_dot(sh_ring + k*64     + half*32, udr);
      float acc1 = proj_dot(sh_ring + (8+k)*64 + half*32, udr);
      acc0 += __shfl_xor(acc0, 32);
      acc1 += __shfl_xor(acc1, 32);
      acc0 *= C2; acc1 *= C2;
      float acc0n = __shfl_down(acc0, 1);
      float acc1n = __shfl_down(acc1, 1);
      if (l < 32 && !(l & 1)) {
        uint2 w; w.x = pk2(acc0, acc0n); w.y = pk2(acc1, acc1n);
        sh_hp[(t0+k)*HPS + (l >> 1)] = w;
      }
    }
    // ---- hw batch for t0..t0+7, both elements ----
    {
      int r8 = l >> 3, c8 = l & 7;
      uint4 hv0 = *(const uint4*)(sh_ring + r8*64     + c8*8);
      uint4 hv1 = *(const uint4*)(sh_ring + (8+r8)*64 + c8*8);
      const f4v* w4 = (const f4v*)&sh_wo2f[c8*8];
      f4v wa = w4[0], wb = w4[1];
      half2_t h0, h1, h2, h3;
      h0=bch(hv0.x); h1=bch(hv0.y); h2=bch(hv0.z); h3=bch(hv0.w);
      float p0 = (float)h0.x*wa.x;
      p0 = fmaf((float)h0.y, wa.y, p0); p0 = fmaf((float)h1.x, wa.z, p0);
      p0 = fmaf((float)h1.y, wa.w, p0); p0 = fmaf((float)h2.x, wb.x, p0);
      p0 = fmaf((float)h2.y, wb.y, p0); p0 = fmaf((float)h3.x, wb.z, p0);
      p0 = fmaf((float)h3.y, wb.w, p0);
      h0=bch(hv1.x); h1=bch(hv1.y); h2=bch(hv1.z); h3=bch(hv1.w);
      float p1 = (float)h0.x*wa.x;
      p1 = fmaf((float)h0.y, wa.y, p1); p1 = fmaf((float)h1.x, wa.z, p1);
      p1 = fmaf((float)h1.y, wa.w, p1); p1 = fmaf((float)h2.x, wb.x, p1);
      p1 = fmaf((float)h2.y, wb.y, p1); p1 = fmaf((float)h3.x, wb.z, p1);
      p1 = fmaf((float)h3.y, wb.w, p1);
      p0 += __shfl_xor(p0, 1); p1 += __shfl_xor(p1, 1);
      p0 += __shfl_xor(p0, 2); p1 += __shfl_xor(p1, 2);
      p0 += __shfl_xor(p0, 4); p1 += __shfl_xor(p1, 4);
      if (c8 == 0) {
        uint2 w; w.x = __builtin_bit_cast(unsigned, p0);
        w.y = __builtin_bit_cast(unsigned, p1);
        sh_hp[(t0+r8)*HPS + 16] = w;
      }
    }
  }

  // ---------------- decoder prep ----------------
  sh_hT0[l] = hprev0;                    // x dead; union reuse
  sh_hT1[l] = hprev1;
  float dprev0, dprev1;
  {  // d0 = h_T @ W_init.T + b_init, both elements (shared W_init row)
    const f4v* wi = (const f4v*)(W_init + l*64);
    const f4v* hbA = (const f4v*)sh_hT0;
    const f4v* hbB = (const f4v*)sh_hT1;
    f2 a0={0,0}, a1={0,0}, c0={0,0}, c1v={0,0};
    #pragma unroll
    for (int k = 0; k < 16; ++k) {
      f4v wv = wi[k]; f4v hA = hbA[k]; f4v hB = hbB[k];
      a0 = pkfma(wv.xy, hA.xy, a0);  a1 = pkfma(wv.zw, hA.zw, a1);
      c0 = pkfma(wv.xy, hB.xy, c0);  c1v = pkfma(wv.zw, hB.zw, c1v);
    }
    float bi = b_init[l];
    dprev0 = bi + (a0.x + a0.y) + (a1.x + a1.y);
    dprev1 = bi + (c0.x + c0.y) + (c1v.x + c1v.y);
  }
  {  // reload GRU weights with decoder W_hh
    const f4v* wp = (const f4v*)W_hh_d;
    #pragma unroll
    for (int k = 0; k < 16; ++k) {
      f4v vr = wp[l*16 + k];
      f4v vz = wp[(64 + l)*16 + k];
      f4v vn = wp[(128 + l)*16 + k];
      wr_r[2*k] = pk2(vr.x, vr.y); wr_r[2*k+1] = pk2(vr.z, vr.w);
      wr_z[2*k] = pk2(vz.x, vz.y); wr_z[2*k+1] = pk2(vz.z, vz.w);
      wr_n[2*k] = pk2(vn.x, vn.y); wr_n[2*k+1] = pk2(vn.z, vn.w);
    }
  }
  wih0 = W_ih_d[l]; wih1 = W_ih_d[64+l]; wih2 = W_ih_d[128+l];
  bb0  = b_ih_d[l] + b_hh_d[l];
  bb1  = b_ih_d[64+l] + b_hh_d[64+l];
  bih2 = b_ih_d[128+l]; bhh2 = b_hh_d[128+l];
  {  // W_d row -> udr
    const f2* up = (const f2*)(W_d + a*64 + half*32);
    #pragma unroll
    for (int k = 0; k < 16; ++k) { f2 f = up[k]; udr[k] = pk2(f.x, f.y); }
  }
  float wout1 = W_out[l];
  uint2 hwA = sh_hp[l*HPS + 16];         // hw at t=l
  uint2 hwB = sh_hp[(64+l)*HPS + 16];    // hw at t=64+l
  float hw00 = __builtin_bit_cast(float, hwA.x);  // elem0, row t0
  float hw01 = __builtin_bit_cast(float, hwA.y);  // elem1, row t0
  float hw10 = __builtin_bit_cast(float, hwB.x);  // elem0, row t1
  float hw11 = __builtin_bit_cast(float, hwB.y);  // elem1, row t1
  float oprev0 = y0[0], oprev1 = oprev0;
  float bo = b_out[0];
  float c1;                              // log2e * sum(v_d)
  {
    float sv = v_d[a];
    sv += __shfl_xor(sv, 16); sv += __shfl_xor(sv, 8);
    sv += __shfl_xor(sv, 4);  sv += __shfl_xor(sv, 2); sv += __shfl_xor(sv, 1);
    c1 = LOG2E * sv;
  }
  sh_ring[l]        = (_Float16)dprev0;  // d0 in ring row 0
  sh_ring[8*64 + l] = (_Float16)dprev1;  // d1 in ring row 8

  const uint2* hpr0 = sh_hp + l*HPS;
  const uint2* hpr1 = sh_hp + (64 + l)*HPS;

  // ---------------- decoder: 24 steps, both elements ----------------
  #pragma unroll 1
  for (int s = 0; s < HOR; ++s) {
    float ar0=0,ar1=0,az0=0,az1=0,an0=0,an1=0;
    float br0=0,br1=0,bz0=0,bz1=0,bn0=0,bn1=0;
    gru_mv(sh_ring,          wr_r, wr_z, wr_n, ar0,ar1,az0,az1,an0,an1);
    gru_mv(sh_ring + 8*64,   wr_r, wr_z, wr_n, br0,br1,bz0,bz1,bn0,bn1);
    float r0 = fsig(fmaf(oprev0, wih0, bb0) + ar0 + ar1);
    float r1 = fsig(fmaf(oprev1, wih0, bb0) + br0 + br1);
    float z0 = fsig(fmaf(oprev0, wih1, bb1) + az0 + az1);
    float z1 = fsig(fmaf(oprev1, wih1, bb1) + bz0 + bz1);
    float n0 = ftanh(fmaf(oprev0, wih2, bih2) + r0 * (an0 + an1 + bhh2));
    float n1 = ftanh(fmaf(oprev1, wih2, bih2) + r1 * (bn0 + bn1 + bhh2));
    float dnew0 = fmaf(z0, dprev0 - n0, n0);
    float dnew1 = fmaf(z1, dprev1 - n1, n1);
    dprev0 = dnew0; dprev1 = dnew1;
    sh_ring[l]        = (_Float16)dnew0;
    sh_ring[8*64 + l] = (_Float16)dnew1;
    // d_proj (pre-scaled C2), both elements
    {
      float acc0 = proj_dot(sh_ring + half*32,        udr);
      float acc1 = proj_dot(sh_ring + 8*64 + half*32, udr);
      acc0 += __shfl_xor(acc0, 32);
      acc1 += __shfl_xor(acc1, 32);
      if (l < 32) { sh_dp0[l] = C2 * acc0; sh_dp1[l] = C2 * acc1; }
    }
    // scores rows t0=l, t1=64+l, both elements
    float rs00=0, rs10=0, rs01=0, rs11=0;   // rs{row}{elem}
    #pragma unroll
    for (int j2 = 0; j2 < 8; ++j2) {
      f4v dA = *(const f4v*)&sh_dp0[4*j2];
      f4v dB = *(const f4v*)&sh_dp1[4*j2];
      uint2 pa0 = hpr0[2*j2], pb0 = hpr0[2*j2+1];
      uint2 pa1 = hpr1[2*j2], pb1 = hpr1[2*j2+1];
      float v0 = v_d[4*j2+0], v1 = v_d[4*j2+1], v2 = v_d[4*j2+2], v3 = v_d[4*j2+3];
      half2_t qa, qb;
      qa = bch(pa0.x); qb = bch(pb0.x);     // elem0, row t0
      rs00 = fmaf(v0, frcp(1.f+fexp2(dA.x+(float)qa.x)), rs00);
      rs00 = fmaf(v1, frcp(1.f+fexp2(dA.y+(float)qa.y)), rs00);
      rs00 = fmaf(v2, frcp(1.f+fexp2(dA.z+(float)qb.x)), rs00);
      rs00 = fmaf(v3, frcp(1.f+fexp2(dA.w+(float)qb.y)), rs00);
      qa = bch(pa1.x); qb = bch(pb1.x);     // elem0, row t1
      rs10 = fmaf(v0, frcp(1.f+fexp2(dA.x+(float)qa.x)), rs10);
      rs10 = fmaf(v1, frcp(1.f+fexp2(dA.y+(float)qa.y)), rs10);
      rs10 = fmaf(v2, frcp(1.f+fexp2(dA.z+(float)qb.x)), rs10);
      rs10 = fmaf(v3, frcp(1.f+fexp2(dA.w+(float)qb.y)), rs10);
      qa = bch(pa0.y); qb = bch(pb0.y);     // elem1, row t0
      rs01 = fmaf(v0, frcp(1.f+fexp2(dB.x+(float)qa.x)), rs01);
      rs01 = fmaf(v1, frcp(1.f+fexp2(dB.y+(float)qa.y)), rs01);
      rs01 = fmaf(v2, frcp(1.f+fexp2(dB.z+(float)qb.x)), rs01);
      rs01 = fmaf(v3, frcp(1.f+fexp2(dB.w+(float)qb.y)), rs01);
      qa = bch(pa1.y); qb = bch(pb1.y);     // elem1, row t1
      rs11 = fmaf(v0, frcp(1.f+fexp2(dB.x+(float)qa.x)), rs11);
      rs11 = fmaf(v1, frcp(1.f+fexp2(dB.y+(float)qa.y)), rs11);
      rs11 = fmaf(v2, frcp(1.f+fexp2(dB.z+(float)qb.x)), rs11);
      rs11 = fmaf(v3, frcp(1.f+fexp2(dB.w+(float)qb.y)), rs11);
    }
    float e00 = fexp2(fmaf(-C2, rs00, c1));
    float e10 = fexp2(fmaf(-C2, rs10, c1));
    float e01 = fexp2(fmaf(-C2, rs01, c1));
    float e11 = fexp2(fmaf(-C2, rs11, c1));
    // six interleaved wave reductions
    float p0a = e00 + e10;
    float p1a = fmaf(e00, hw00, e10 * hw10);
    float p2a = wout1 * dnew0;
    float p0b = e01 + e11;
    float p1b = fmaf(e01, hw01, e11 * hw11);
    float p2b = wout1 * dnew1;
    #pragma unroll
    for (int off = 32; off > 0; off >>= 1) {
      p0a += __shfl_xor(p0a, off);
      p1a += __shfl_xor(p1a, off);
      p2a += __shfl_xor(p2a, off);
      p0b += __shfl_xor(p0b, off);
      p1b += __shfl_xor(p1b, off);
      p2b += __shfl_xor(p2b, off);
    }
    float o0 = fmaf(p1a, frcp(p0a), p2a + bo);
    float o1 = fmaf(p1b, frcp(p0b), p2b + bo);
    if (l == 0) {
      out[(size_t)b0 * HOR + s] = o0;
      out[(size_t)b1 * HOR + s] = o1;
    }
    oprev0 = o0; oprev1 = o1;
  }
}

extern "C" void kernel_launch(void* const* d_in, const int* in_sizes, int n_in,
                              void* d_out, int out_size, void* d_ws, size_t ws_size,
                              hipStream_t stream) {
  const float* x      = (const float*)d_in[0];
  const float* W_ih_e = (const float*)d_in[1];
  const float* W_hh_e = (const float*)d_in[2];
  const float* b_ih_e = (const float*)d_in[3];
  const float* b_hh_e = (const float*)d_in[4];
  // d_in[5..8] = W_e, U_e, b_e, v_e : dead (softmax over size-1 axis == 1)
  const float* W_init = (const float*)d_in[9];
  const float* b_init = (const float*)d_in[10];
  const float* W_ih_d = (const float*)d_in[11];
  const float* W_hh_d = (const float*)d_in[12];
  const float* b_ih_d = (const float*)d_in[13];
  const float* b_hh_d = (const float*)d_in[14];
  const float* W_d    = (const float*)d_in[15];
  const float* U_d    = (const float*)d_in[16];
  const float* v_d    = (const float*)d_in[17];
  const float* W_out  = (const float*)d_in[18];
  const float* b_out  = (const float*)d_in[19];
  const float* y0     = (const float*)d_in[20];
  float* outp = (float*)d_out;

  darnn_kernel<<<BATCH/2, 64, 0, stream>>>(x, W_ih_e, W_hh_e, b_ih_e, b_hh_e,
      W_init, b_init, W_ih_d, W_hh_d, b_ih_d, b_hh_d, W_d, U_d, v_d, W_out,
      b_out, y0, outp);
}

// Round 11
// 405.230 us; speedup vs baseline: 1.9295x; 1.0016x over previous
//
#include <hip/hip_runtime.h>
#include <math.h>

#define BATCH 4096
#define T 128
#define HOR 24
#define HPS 17                     // hp row stride in uint2 units

#define LOG2E 1.44269504088896f
#define C2    2.88539008177793f   // 2*log2(e)

typedef _Float16 half2_t __attribute__((ext_vector_type(2)));
typedef float f2  __attribute__((ext_vector_type(2)));
typedef float f4v __attribute__((ext_vector_type(4)));

__device__ __forceinline__ float fexp2(float x){ return __builtin_amdgcn_exp2f(x); }
__device__ __forceinline__ float frcp(float x){ return __builtin_amdgcn_rcpf(x); }
__device__ __forceinline__ float fsig(float x){ return frcp(1.0f + fexp2(-LOG2E*x)); }
__device__ __forceinline__ float ftanh(float x){ return fmaf(-2.0f, frcp(1.0f + fexp2(C2*x)), 1.0f); }
__device__ __forceinline__ half2_t bch(unsigned u){ return __builtin_bit_cast(half2_t,u); }
__device__ __forceinline__ unsigned pk2(float a,float b){ return __builtin_bit_cast(unsigned, __builtin_amdgcn_cvt_pkrtz(a,b)); }
__device__ __forceinline__ float fdot2f(half2_t a, half2_t b, float c){
#if __has_builtin(__builtin_amdgcn_fdot2)
  return __builtin_amdgcn_fdot2(a,b,c,false);
#else
  return fmaf((float)a.x,(float)b.x, fmaf((float)a.y,(float)b.y,c));
#endif
}
__device__ __forceinline__ f2 pkfma(f2 a, f2 b, f2 c){ return __builtin_elementwise_fma(a,b,c); }

// ---- DPP wave64 reduction: full-rate VALU, no LDS pipe (vs ds_bpermute) ----
// update_dpp control args must be immediates -> template parameters.
template <int CTRL, int RMASK>
__device__ __forceinline__ float dpp_add(float v) {
  int s = __builtin_amdgcn_update_dpp(0, __builtin_bit_cast(int, v), CTRL, RMASK, 0xf, true);
  return v + __builtin_bit_cast(float, s);
}
__device__ __forceinline__ float wavesum_dpp(float v) {
  v = dpp_add<0x111, 0xf>(v);   // row_shr:1
  v = dpp_add<0x112, 0xf>(v);   // row_shr:2
  v = dpp_add<0x114, 0xf>(v);   // row_shr:4
  v = dpp_add<0x118, 0xf>(v);   // row_shr:8
  v = dpp_add<0x142, 0xa>(v);   // row_bcast:15 -> rows 1,3
  v = dpp_add<0x143, 0xc>(v);   // row_bcast:31 -> rows 2,3
  return v;                     // total in lane 63
}
__device__ __forceinline__ float rdl63(float v){
  return __builtin_bit_cast(float, __builtin_amdgcn_readlane(__builtin_bit_cast(int, v), 63));
}

__device__ __forceinline__ void gru_mv(const _Float16* hrow,
    const unsigned* wr_r, const unsigned* wr_z, const unsigned* wr_n,
    float& ar0, float& ar1, float& az0, float& az1, float& an0, float& an1)
{
  const uint4* hq = (const uint4*)hrow;      // broadcast reads (uniform addr)
  #pragma unroll
  for (int q = 0; q < 8; ++q) {
    uint4 hv = hq[q];
    ar0 = fdot2f(bch(hv.x), bch(wr_r[4*q+0]), ar0);
    az0 = fdot2f(bch(hv.x), bch(wr_z[4*q+0]), az0);
    an0 = fdot2f(bch(hv.x), bch(wr_n[4*q+0]), an0);
    ar1 = fdot2f(bch(hv.y), bch(wr_r[4*q+1]), ar1);
    az1 = fdot2f(bch(hv.y), bch(wr_z[4*q+1]), az1);
    an1 = fdot2f(bch(hv.y), bch(wr_n[4*q+1]), an1);
    ar0 = fdot2f(bch(hv.z), bch(wr_r[4*q+2]), ar0);
    az0 = fdot2f(bch(hv.z), bch(wr_z[4*q+2]), az0);
    an0 = fdot2f(bch(hv.z), bch(wr_n[4*q+2]), an0);
    ar1 = fdot2f(bch(hv.w), bch(wr_r[4*q+3]), ar1);
    az1 = fdot2f(bch(hv.w), bch(wr_z[4*q+3]), az1);
    an1 = fdot2f(bch(hv.w), bch(wr_n[4*q+3]), an1);
  }
}

__device__ __forceinline__ float proj_dot(const _Float16* base, const unsigned* udr)
{
  float acc = 0.f;
  const uint4* hb = (const uint4*)base;
  #pragma unroll
  for (int q = 0; q < 4; ++q) {
    uint4 hv = hb[q];
    acc = fdot2f(bch(hv.x), bch(udr[4*q+0]), acc);
    acc = fdot2f(bch(hv.y), bch(udr[4*q+1]), acc);
    acc = fdot2f(bch(hv.z), bch(udr[4*q+2]), acc);
    acc = fdot2f(bch(hv.w), bch(udr[4*q+3]), acc);
  }
  return acc;
}

// TWO batch elements per wave (blockDim=64, grid=BATCH/2). Wave-synchronous,
// ZERO barriers. R11 = proven R8 kernel + ONE change: decoder reductions via
// DPP (VALU-rate) instead of ds_bpermute shuffles — clean bisect of R10's
// failure (R10 changed MFMA Hp/hw AND DPP at once; one of them is wrong).
// __launch_bounds__(64,2): 256-reg budget. DO NOT raise (R5: spills, 80x FETCH).
__global__ __launch_bounds__(64, 2)
void darnn_kernel(const float* __restrict__ x,
                  const float* __restrict__ W_ih_e, const float* __restrict__ W_hh_e,
                  const float* __restrict__ b_ih_e, const float* __restrict__ b_hh_e,
                  const float* __restrict__ W_init, const float* __restrict__ b_init,
                  const float* __restrict__ W_ih_d, const float* __restrict__ W_hh_d,
                  const float* __restrict__ b_ih_d, const float* __restrict__ b_hh_d,
                  const float* __restrict__ W_d, const float* __restrict__ U_d,
                  const float* __restrict__ v_d, const float* __restrict__ W_out,
                  const float* __restrict__ b_out, const float* __restrict__ y0,
                  float* __restrict__ out)
{
  const int l = threadIdx.x;            // 0..63
  const int b0 = 2*blockIdx.x, b1 = b0 + 1;
  const int a    = l & 31;
  const int half = l >> 5;

  __shared__ __align__(16) unsigned char smem[20480];
  uint2*    sh_hp   = (uint2*)smem;
  _Float16* sh_ring = (_Float16*)(smem + 17408);
  _Float16* sh_x0   = (_Float16*)(smem + 19456);
  _Float16* sh_x1   = (_Float16*)(smem + 19712);
  float*    sh_wo2f = (float*)(smem + 19968);
  float*    sh_hT0  = (float*)(smem + 19456);
  float*    sh_hT1  = (float*)(smem + 19712);
  float*    sh_dp0  = (float*)(smem + 20224);
  float*    sh_dp1  = (float*)(smem + 20352);

  unsigned wr_r[32], wr_z[32], wr_n[32];  // shared GRU W_hh rows fp16 (96 VGPR)
  unsigned udr[16];                        // shared U_d (later W_d) row a, half

  // ---------------- stage ----------------
  {
    const f4v* wp = (const f4v*)W_hh_e;
    #pragma unroll
    for (int k = 0; k < 16; ++k) {
      f4v vr = wp[l*16 + k];
      f4v vz = wp[(64 + l)*16 + k];
      f4v vn = wp[(128 + l)*16 + k];
      wr_r[2*k] = pk2(vr.x, vr.y); wr_r[2*k+1] = pk2(vr.z, vr.w);
      wr_z[2*k] = pk2(vz.x, vz.y); wr_z[2*k+1] = pk2(vz.z, vz.w);
      wr_n[2*k] = pk2(vn.x, vn.y); wr_n[2*k+1] = pk2(vn.z, vn.w);
    }
  }
  float wih0 = W_ih_e[l], wih1 = W_ih_e[64+l], wih2 = W_ih_e[128+l];
  float bb0  = b_ih_e[l] + b_hh_e[l];
  float bb1  = b_ih_e[64+l] + b_hh_e[64+l];
  float bih2 = b_ih_e[128+l], bhh2 = b_hh_e[128+l];
  sh_wo2f[l] = W_out[64 + l];
  {
    f2 g0 = ((const f2*)(x + (size_t)b0 * T))[l];
    f2 g1 = ((const f2*)(x + (size_t)b1 * T))[l];
    ((unsigned*)sh_x0)[l] = pk2(g0.x, g0.y);
    ((unsigned*)sh_x1)[l] = pk2(g1.x, g1.y);
  }
  sh_ring[7*64  + l] = (_Float16)0.0f;   // h_{-1} elem0
  sh_ring[15*64 + l] = (_Float16)0.0f;   // h_{-1} elem1
  {  // U_d row a, half -> registers
    const f2* up = (const f2*)(U_d + a*64 + half*32);
    #pragma unroll
    for (int k = 0; k < 16; ++k) { f2 f = up[k]; udr[k] = pk2(f.x, f.y); }
  }

  // ---------------- encoder: 128 steps, both elements ----------------
  // input-attention is identity (softmax over size-1 axis == 1).
  float hprev0 = 0.0f, hprev1 = 0.0f;
  #pragma unroll 1
  for (int t0 = 0; t0 < T; t0 += 8) {
    #pragma unroll
    for (int u = 0; u < 8; ++u) {
      const int t = t0 + u;
      float ar0=0,ar1=0,az0=0,az1=0,an0=0,an1=0;
      float br0=0,br1=0,bz0=0,bz1=0,bn0=0,bn1=0;
      gru_mv(sh_ring + ((t+7)&7)*64,      wr_r, wr_z, wr_n, ar0,ar1,az0,az1,an0,an1);
      gru_mv(sh_ring + (8+((t+7)&7))*64,  wr_r, wr_z, wr_n, br0,br1,bz0,bz1,bn0,bn1);
      float xt0 = (float)sh_x0[t], xt1 = (float)sh_x1[t];
      float r0 = fsig(fmaf(xt0, wih0, bb0) + ar0 + ar1);
      float r1 = fsig(fmaf(xt1, wih0, bb0) + br0 + br1);
      float z0 = fsig(fmaf(xt0, wih1, bb1) + az0 + az1);
      float z1 = fsig(fmaf(xt1, wih1, bb1) + bz0 + bz1);
      float n0 = ftanh(fmaf(xt0, wih2, bih2) + r0 * (an0 + an1 + bhh2));
      float n1 = ftanh(fmaf(xt1, wih2, bih2) + r1 * (bn0 + bn1 + bhh2));
      hprev0 = fmaf(z0, hprev0 - n0, n0);
      hprev1 = fmaf(z1, hprev1 - n1, n1);
      sh_ring[(t&7)*64 + l]     = (_Float16)hprev0;
      sh_ring[(8+(t&7))*64 + l] = (_Float16)hprev1;
    }
    // ---- Hp batch for t0..t0+7, both elements ----
    #pragma unroll
    for (int k = 0; k < 8; ++k) {
      float acc0 = proj_dot(sh_ring + k*64     + half*32, udr);
      float acc1 = proj_dot(sh_ring + (8+k)*64 + half*32, udr);
      acc0 += __shfl_xor(acc0, 32);
      acc1 += __shfl_xor(acc1, 32);
      acc0 *= C2; acc1 *= C2;
      float acc0n = __shfl_down(acc0, 1);
      float acc1n = __shfl_down(acc1, 1);
      if (l < 32 && !(l & 1)) {
        uint2 w; w.x = pk2(acc0, acc0n); w.y = pk2(acc1, acc1n);
        sh_hp[(t0+k)*HPS + (l >> 1)] = w;
      }
    }
    // ---- hw batch for t0..t0+7, both elements ----
    {
      int r8 = l >> 3, c8 = l & 7;
      uint4 hv0 = *(const uint4*)(sh_ring + r8*64     + c8*8);
      uint4 hv1 = *(const uint4*)(sh_ring + (8+r8)*64 + c8*8);
      const f4v* w4 = (const f4v*)&sh_wo2f[c8*8];
      f4v wa = w4[0], wb = w4[1];
      half2_t h0, h1, h2, h3;
      h0=bch(hv0.x); h1=bch(hv0.y); h2=bch(hv0.z); h3=bch(hv0.w);
      float p0 = (float)h0.x*wa.x;
      p0 = fmaf((float)h0.y, wa.y, p0); p0 = fmaf((float)h1.x, wa.z, p0);
      p0 = fmaf((float)h1.y, wa.w, p0); p0 = fmaf((float)h2.x, wb.x, p0);
      p0 = fmaf((float)h2.y, wb.y, p0); p0 = fmaf((float)h3.x, wb.z, p0);
      p0 = fmaf((float)h3.y, wb.w, p0);
      h0=bch(hv1.x); h1=bch(hv1.y); h2=bch(hv1.z); h3=bch(hv1.w);
      float p1 = (float)h0.x*wa.x;
      p1 = fmaf((float)h0.y, wa.y, p1); p1 = fmaf((float)h1.x, wa.z, p1);
      p1 = fmaf((float)h1.y, wa.w, p1); p1 = fmaf((float)h2.x, wb.x, p1);
      p1 = fmaf((float)h2.y, wb.y, p1); p1 = fmaf((float)h3.x, wb.z, p1);
      p1 = fmaf((float)h3.y, wb.w, p1);
      p0 += __shfl_xor(p0, 1); p1 += __shfl_xor(p1, 1);
      p0 += __shfl_xor(p0, 2); p1 += __shfl_xor(p1, 2);
      p0 += __shfl_xor(p0, 4); p1 += __shfl_xor(p1, 4);
      if (c8 == 0) {
        uint2 w; w.x = __builtin_bit_cast(unsigned, p0);
        w.y = __builtin_bit_cast(unsigned, p1);
        sh_hp[(t0+r8)*HPS + 16] = w;
      }
    }
  }

  // ---------------- decoder prep ----------------
  sh_hT0[l] = hprev0;                    // x dead; union reuse
  sh_hT1[l] = hprev1;
  float dprev0, dprev1;
  {  // d0 = h_T @ W_init.T + b_init, both elements (shared W_init row)
    const f4v* wi = (const f4v*)(W_init + l*64);
    const f4v* hbA = (const f4v*)sh_hT0;
    const f4v* hbB = (const f4v*)sh_hT1;
    f2 a0={0,0}, a1={0,0}, c0={0,0}, c1v={0,0};
    #pragma unroll
    for (int k = 0; k < 16; ++k) {
      f4v wv = wi[k]; f4v hA = hbA[k]; f4v hB = hbB[k];
      a0 = pkfma(wv.xy, hA.xy, a0);  a1 = pkfma(wv.zw, hA.zw, a1);
      c0 = pkfma(wv.xy, hB.xy, c0);  c1v = pkfma(wv.zw, hB.zw, c1v);
    }
    float bi = b_init[l];
    dprev0 = bi + (a0.x + a0.y) + (a1.x + a1.y);
    dprev1 = bi + (c0.x + c0.y) + (c1v.x + c1v.y);
  }
  {  // reload GRU weights with decoder W_hh
    const f4v* wp = (const f4v*)W_hh_d;
    #pragma unroll
    for (int k = 0; k < 16; ++k) {
      f4v vr = wp[l*16 + k];
      f4v vz = wp[(64 + l)*16 + k];
      f4v vn = wp[(128 + l)*16 + k];
      wr_r[2*k] = pk2(vr.x, vr.y); wr_r[2*k+1] = pk2(vr.z, vr.w);
      wr_z[2*k] = pk2(vz.x, vz.y); wr_z[2*k+1] = pk2(vz.z, vz.w);
      wr_n[2*k] = pk2(vn.x, vn.y); wr_n[2*k+1] = pk2(vn.z, vn.w);
    }
  }
  wih0 = W_ih_d[l]; wih1 = W_ih_d[64+l]; wih2 = W_ih_d[128+l];
  bb0  = b_ih_d[l] + b_hh_d[l];
  bb1  = b_ih_d[64+l] + b_hh_d[64+l];
  bih2 = b_ih_d[128+l]; bhh2 = b_hh_d[128+l];
  {  // W_d row -> udr
    const f2* up = (const f2*)(W_d + a*64 + half*32);
    #pragma unroll
    for (int k = 0; k < 16; ++k) { f2 f = up[k]; udr[k] = pk2(f.x, f.y); }
  }
  float wout1 = W_out[l];
  uint2 hwA = sh_hp[l*HPS + 16];         // hw at t=l
  uint2 hwB = sh_hp[(64+l)*HPS + 16];    // hw at t=64+l
  float hw00 = __builtin_bit_cast(float, hwA.x);  // elem0, row t0
  float hw01 = __builtin_bit_cast(float, hwA.y);  // elem1, row t0
  float hw10 = __builtin_bit_cast(float, hwB.x);  // elem0, row t1
  float hw11 = __builtin_bit_cast(float, hwB.y);  // elem1, row t1
  float oprev0 = y0[0], oprev1 = oprev0;
  float bo = b_out[0];
  float c1;                              // log2e * sum(v_d)
  {
    float sv = v_d[a];
    sv += __shfl_xor(sv, 16); sv += __shfl_xor(sv, 8);
    sv += __shfl_xor(sv, 4);  sv += __shfl_xor(sv, 2); sv += __shfl_xor(sv, 1);
    c1 = LOG2E * sv;
  }
  sh_ring[l]        = (_Float16)dprev0;  // d0 in ring row 0
  sh_ring[8*64 + l] = (_Float16)dprev1;  // d1 in ring row 8

  const uint2* hpr0 = sh_hp + l*HPS;
  const uint2* hpr1 = sh_hp + (64 + l)*HPS;

  // ---------------- decoder: 24 steps, both elements ----------------
  #pragma unroll 1
  for (int s = 0; s < HOR; ++s) {
    float ar0=0,ar1=0,az0=0,az1=0,an0=0,an1=0;
    float br0=0,br1=0,bz0=0,bz1=0,bn0=0,bn1=0;
    gru_mv(sh_ring,          wr_r, wr_z, wr_n, ar0,ar1,az0,az1,an0,an1);
    gru_mv(sh_ring + 8*64,   wr_r, wr_z, wr_n, br0,br1,bz0,bz1,bn0,bn1);
    float r0 = fsig(fmaf(oprev0, wih0, bb0) + ar0 + ar1);
    float r1 = fsig(fmaf(oprev1, wih0, bb0) + br0 + br1);
    float z0 = fsig(fmaf(oprev0, wih1, bb1) + az0 + az1);
    float z1 = fsig(fmaf(oprev1, wih1, bb1) + bz0 + bz1);
    float n0 = ftanh(fmaf(oprev0, wih2, bih2) + r0 * (an0 + an1 + bhh2));
    float n1 = ftanh(fmaf(oprev1, wih2, bih2) + r1 * (bn0 + bn1 + bhh2));
    float dnew0 = fmaf(z0, dprev0 - n0, n0);
    float dnew1 = fmaf(z1, dprev1 - n1, n1);
    dprev0 = dnew0; dprev1 = dnew1;
    sh_ring[l]        = (_Float16)dnew0;
    sh_ring[8*64 + l] = (_Float16)dnew1;
    // d_proj (pre-scaled C2), both elements
    {
      float acc0 = proj_dot(sh_ring + half*32,        udr);
      float acc1 = proj_dot(sh_ring + 8*64 + half*32, udr);
      acc0 += __shfl_xor(acc0, 32);
      acc1 += __shfl_xor(acc1, 32);
      if (l < 32) { sh_dp0[l] = C2 * acc0; sh_dp1[l] = C2 * acc1; }
    }
    // scores rows t0=l, t1=64+l, both elems; hp pairs are consecutive a
    float rs00=0, rs10=0, rs01=0, rs11=0;   // rs{row}{elem}
    #pragma unroll
    for (int j2 = 0; j2 < 8; ++j2) {
      f4v dA = *(const f4v*)&sh_dp0[4*j2];
      f4v dB = *(const f4v*)&sh_dp1[4*j2];
      uint2 pa0 = hpr0[2*j2], pb0 = hpr0[2*j2+1];
      uint2 pa1 = hpr1[2*j2], pb1 = hpr1[2*j2+1];
      float v0 = v_d[4*j2+0], v1 = v_d[4*j2+1], v2 = v_d[4*j2+2], v3 = v_d[4*j2+3];
      half2_t qa, qb;
      qa = bch(pa0.x); qb = bch(pb0.x);     // elem0, row t0
      rs00 = fmaf(v0, frcp(1.f+fexp2(dA.x+(float)qa.x)), rs00);
      rs00 = fmaf(v1, frcp(1.f+fexp2(dA.y+(float)qa.y)), rs00);
      rs00 = fmaf(v2, frcp(1.f+fexp2(dA.z+(float)qb.x)), rs00);
      rs00 = fmaf(v3, frcp(1.f+fexp2(dA.w+(float)qb.y)), rs00);
      qa = bch(pa1.x); qb = bch(pb1.x);     // elem0, row t1
      rs10 = fmaf(v0, frcp(1.f+fexp2(dA.x+(float)qa.x)), rs10);
      rs10 = fmaf(v1, frcp(1.f+fexp2(dA.y+(float)qa.y)), rs10);
      rs10 = fmaf(v2, frcp(1.f+fexp2(dA.z+(float)qb.x)), rs10);
      rs10 = fmaf(v3, frcp(1.f+fexp2(dA.w+(float)qb.y)), rs10);
      qa = bch(pa0.y); qb = bch(pb0.y);     // elem1, row t0
      rs01 = fmaf(v0, frcp(1.f+fexp2(dB.x+(float)qa.x)), rs01);
      rs01 = fmaf(v1, frcp(1.f+fexp2(dB.y+(float)qa.y)), rs01);
      rs01 = fmaf(v2, frcp(1.f+fexp2(dB.z+(float)qb.x)), rs01);
      rs01 = fmaf(v3, frcp(1.f+fexp2(dB.w+(float)qb.y)), rs01);
      qa = bch(pa1.y); qb = bch(pb1.y);     // elem1, row t1
      rs11 = fmaf(v0, frcp(1.f+fexp2(dB.x+(float)qa.x)), rs11);
      rs11 = fmaf(v1, frcp(1.f+fexp2(dB.y+(float)qa.y)), rs11);
      rs11 = fmaf(v2, frcp(1.f+fexp2(dB.z+(float)qb.x)), rs11);
      rs11 = fmaf(v3, frcp(1.f+fexp2(dB.w+(float)qb.y)), rs11);
    }
    float e00 = fexp2(fmaf(-C2, rs00, c1));
    float e10 = fexp2(fmaf(-C2, rs10, c1));
    float e01 = fexp2(fmaf(-C2, rs01, c1));
    float e11 = fexp2(fmaf(-C2, rs11, c1));
    // six DPP reductions (VALU-rate cross-lane; no LDS pipe)
    float P0a = rdl63(wavesum_dpp(e00 + e10));
    float P1a = rdl63(wavesum_dpp(fmaf(e00, hw00, e10 * hw10)));
    float P2a = rdl63(wavesum_dpp(wout1 * dnew0));
    float P0b = rdl63(wavesum_dpp(e01 + e11));
    float P1b = rdl63(wavesum_dpp(fmaf(e01, hw01, e11 * hw11)));
    float P2b = rdl63(wavesum_dpp(wout1 * dnew1));
    float o0 = fmaf(P1a, frcp(P0a), P2a + bo);
    float o1 = fmaf(P1b, frcp(P0b), P2b + bo);
    if (l == 0) {
      out[(size_t)b0 * HOR + s] = o0;
      out[(size_t)b1 * HOR + s] = o1;
    }
    oprev0 = o0; oprev1 = o1;
  }
}

extern "C" void kernel_launch(void* const* d_in, const int* in_sizes, int n_in,
                              void* d_out, int out_size, void* d_ws, size_t ws_size,
                              hipStream_t stream) {
  const float* x      = (const float*)d_in[0];
  const float* W_ih_e = (const float*)d_in[1];
  const float* W_hh_e = (const float*)d_in[2];
  const float* b_ih_e = (const float*)d_in[3];
  const float* b_hh_e = (const float*)d_in[4];
  // d_in[5..8] = W_e, U_e, b_e, v_e : dead (softmax over size-1 axis == 1)
  const float* W_init = (const float*)d_in[9];
  const float* b_init = (const float*)d_in[10];
  const float* W_ih_d = (const float*)d_in[11];
  const float* W_hh_d = (const float*)d_in[12];
  const float* b_ih_d = (const float*)d_in[13];
  const float* b_hh_d = (const float*)d_in[14];
  const float* W_d    = (const float*)d_in[15];
  const float* U_d    = (const float*)d_in[16];
  const float* v_d    = (const float*)d_in[17];
  const float* W_out  = (const float*)d_in[18];
  const float* b_out  = (const float*)d_in[19];
  const float* y0     = (const float*)d_in[20];
  float* outp = (float*)d_out;

  darnn_kernel<<<BATCH/2, 64, 0, stream>>>(x, W_ih_e, W_hh_e, b_ih_e, b_hh_e,
      W_init, b_init, W_ih_d, W_hh_d, b_ih_d, b_hh_d, W_d, U_d, v_d, W_out,
      b_out, y0, outp);
}